// Round 5
// baseline (1553.680 us; speedup 1.0000x reference)
//
#include <hip/hip_runtime.h>
#include <math.h>

// ---------------------------------------------------------------------------
// MPNN (NNConv+GRU x3, Set2Set x3, readout).
// R5: A-fragments built directly in registers per consuming lane (no LDS
// round-trip, no barriers in main loop), chunk-paired to halve s-gathers,
// 3-pass split-fp16 MFMA vs pre-split Wbig frags. Split-K x4 + atomics.
// ---------------------------------------------------------------------------

typedef _Float16 f16x8 __attribute__((ext_vector_type(8)));
typedef float f32x4 __attribute__((ext_vector_type(4)));

#define BFRAG_TOTAL (66 * 4 * 4 * 64 * 8)  // 540672 halves per array
#define SSRC_CAP 1024

// graph segment pointers from sorted batch
__global__ void k_gptr(const int* __restrict__ batch, int* __restrict__ gptr,
                       int N, int B) {
  int n = blockIdx.x * 256 + threadIdx.x;
  if (n >= N) return;
  int b = batch[n];
  int bp = (n == 0) ? -1 : batch[n - 1];
  for (int g = bp + 1; g <= b; ++g) gptr[g] = n;
  if (n == N - 1) {
    for (int g = b + 1; g <= B; ++g) gptr[g] = N;
  }
}

__global__ void k_cnt(const int* __restrict__ eidx, int* __restrict__ cnt, int E) {
  int e = blockIdx.x * 256 + threadIdx.x;
  if (e < E) atomicAdd(&cnt[eidx[E + e]], 1);
}

// single-block scan via wave shuffles -> dptr (exclusive CSR pointers)
__global__ __launch_bounds__(1024) void k_scan(const int* __restrict__ cnt,
                                               int* __restrict__ dptr, int N) {
  __shared__ int wsum[16];
  int t = threadIdx.x;
  int lane = t & 63, wid = t >> 6;
  if (t == 0) dptr[0] = 0;
  int running = 0;
  for (int base = 0; base < N; base += 1024) {
    int x = (base + t < N) ? cnt[base + t] : 0;
#pragma unroll
    for (int d = 1; d < 64; d <<= 1) {
      int u = __shfl_up(x, d, 64);
      if (lane >= d) x += u;
    }
    if (lane == 63) wsum[wid] = x;
    __syncthreads();
    if (wid == 0) {
      int y = (lane < 16) ? wsum[lane] : 0;
#pragma unroll
      for (int d = 1; d < 16; d <<= 1) {
        int u = __shfl_up(y, d, 64);
        if (lane >= d) y += u;
      }
      if (lane < 16) wsum[lane] = y;
    }
    __syncthreads();
    int add = running + (wid > 0 ? wsum[wid - 1] : 0);
    if (base + t < N) dptr[base + t + 1] = add + x;
    running += wsum[15];
    __syncthreads();
  }
}

__global__ void k_fill(const int* __restrict__ eidx, const int* __restrict__ dptr,
                       int* __restrict__ fill, int* __restrict__ srcs_s,
                       int* __restrict__ eord, int E) {
  int e = blockIdx.x * 256 + threadIdx.x;
  if (e >= E) return;
  int d = eidx[E + e];
  int pos = dptr[d] + atomicAdd(&fill[d], 1);
  srcs_s[pos] = eidx[e];
  eord[pos] = e;
}

// h1p[k>>1][pos] = float2(h1[pos][2k'], h1[pos][2k'+1]) : k-major pair layout
__global__ __launch_bounds__(256) void k_h1t(const float* __restrict__ eattr,
                                             const int* __restrict__ eord,
                                             const float* __restrict__ nn1_w,
                                             const float* __restrict__ nn1_b,
                                             float2* __restrict__ h1p, int E,
                                             int Epad) {
  __shared__ float a5[128 * 5];
  __shared__ float w5[128 * 5];
  __shared__ float bb[128];
  const int t = threadIdx.x;
  const int p0 = blockIdx.x * 128;
  for (int idx = t; idx < 640; idx += 256) w5[idx] = nn1_w[idx];
  if (t < 128) bb[t] = nn1_b[t];
  if (t < 128) {
    int pos = p0 + t;
    if (pos < E) {
      int e = eord[pos];
      const float* a = eattr + (size_t)e * 5;
#pragma unroll
      for (int q = 0; q < 5; ++q) a5[t * 5 + q] = a[q];
    } else {
#pragma unroll
      for (int q = 0; q < 5; ++q) a5[t * 5 + q] = 0.f;
    }
  }
  __syncthreads();
  const int pl = t & 127, jh = (t >> 7) * 64;
  const int pos = p0 + pl;
  if (pos >= E) return;
  float a0 = a5[pl * 5 + 0], a1 = a5[pl * 5 + 1], a2 = a5[pl * 5 + 2],
        a3 = a5[pl * 5 + 3], a4 = a5[pl * 5 + 4];
#pragma unroll 8
  for (int jj = 0; jj < 64; jj += 2) {
    int j = jh + jj;
    const float* w0 = &w5[j * 5];
    float v0 = fmaxf(bb[j] + a0 * w0[0] + a1 * w0[1] + a2 * w0[2] + a3 * w0[3] +
                         a4 * w0[4], 0.f);
    const float* w1 = &w5[(j + 1) * 5];
    float v1 = fmaxf(bb[j + 1] + a0 * w1[0] + a1 * w1[1] + a2 * w1[2] +
                         a3 * w1[3] + a4 * w1[4], 0.f);
    h1p[(size_t)(j >> 1) * Epad + pos] = make_float2(v0, v1);
  }
}

// Pre-split Wbig into fp16 hi/lo in MFMA B-fragment order:
// flat idx = (((kc*4 + w)*4 + c)*64 + lane)*8 + j
__global__ void k_bsplit(const float* __restrict__ nn2_w,
                         const float* __restrict__ nn2_b,
                         const float* __restrict__ root_w,
                         _Float16* __restrict__ Bh, _Float16* __restrict__ Bl) {
  int idx = blockIdx.x * 256 + threadIdx.x;
  if (idx >= BFRAG_TOTAL) return;
  int j = idx & 7;
  int lane = (idx >> 3) & 63;
  int c = (idx >> 9) & 3;
  int w = (idx >> 11) & 3;
  int kc = idx >> 13;
  int m = w * 32 + ((lane >> 4) << 3) + j;
  int o = c * 16 + (lane & 15);
  int i = m & 63, kl = m >> 6;
  float v;
  if (kc < 64)
    v = nn2_w[(size_t)(i * 64 + o) * 128 + (kc * 2 + kl)];
  else if (kc == 64)
    v = (kl == 0) ? nn2_b[i * 64 + o] : 0.f;
  else
    v = (kl == 0) ? root_w[o * 64 + i] : 0.f;
  _Float16 h = (_Float16)v;
  Bh[idx] = h;
  Bl[idx] = (_Float16)(v - (float)h);
}

// out = relu(x @ lin0_w^T + lin0_b)
__global__ void k_lin0(const float* __restrict__ x, const float* __restrict__ w,
                       const float* __restrict__ b, float* __restrict__ outn, int N) {
  int gid = blockIdx.x * 256 + threadIdx.x;
  int n = gid >> 6, d = gid & 63;
  if (n >= N) return;
  const float* xr = x + (size_t)n * 11;
  const float* wr = w + d * 11;
  float acc = b[d];
#pragma unroll
  for (int f = 0; f < 11; ++f) acc += xr[f] * wr[f];
  outn[(size_t)n * 64 + d] = fmaxf(acc, 0.f);
}

#define SPLIT16(av, ph, pl)                    \
  {                                            \
    _Pragma("unroll") for (int jj = 0; jj < 8; ++jj) { \
      float v_ = (av)[jj];                     \
      _Float16 h_ = (_Float16)v_;              \
      (ph)[jj] = h_;                           \
      (pl)[jj] = (_Float16)(v_ - (float)h_);   \
    }                                          \
  }

// ---------------- fused NNConv: register A-frags, barrier-free K-loop ------
__global__ __launch_bounds__(256, 2) void k_fused(
    const float* __restrict__ outn, const float2* __restrict__ h1p,
    const int* __restrict__ dptr, const int* __restrict__ srcs_s,
    const _Float16* __restrict__ Bh, const _Float16* __restrict__ Bl,
    float* __restrict__ agg2, int N, int Epad) {
  __shared__ int sSrc[SSRC_CAP];
  __shared__ int sP[65];

  const int t = threadIdx.x;
  const int w = t >> 6, lane = t & 63;
  const int lm = lane & 15;        // node within 16-group
  const int klc = w >> 1;          // which h component this wave consumes
  const int i0 = (w & 1) * 32 + (lane >> 4) * 8;  // i-slice base
  const int split = blockIdx.y;
  const int n0 = blockIdx.x * 64;

  if (t < 65) {
    int idx = n0 + t;
    sP[t] = dptr[idx > N ? N : idx];
  }
  __syncthreads();
  const int p0b = sP[0];
  const int EB = sP[64] - p0b;
  const bool useLds = (EB <= SSRC_CAP);
  if (useLds) {
    for (int idx = t; idx < EB; idx += 256) sSrc[idx] = srcs_s[p0b + idx];
  }
  __syncthreads();

  f32x4 acc[4][4];
#pragma unroll
  for (int a = 0; a < 4; ++a)
#pragma unroll
    for (int c = 0; c < 4; ++c) acc[a][c] = (f32x4)(0.f);

  // ---- main loop: 8 chunk-pairs, no barriers ----
  for (int cp = 0; cp < 8; ++cp) {
    const int kcA = split * 16 + cp * 2;
    const int kcB = kcA + 1;
    const float* hA = (const float*)(h1p + (size_t)kcA * Epad);
    const float* hB = (const float*)(h1p + (size_t)kcB * Epad);

    // hoist B frags: 16 independent 16-B loads (L2-resident)
    f16x8 bhA[4], blA[4], bhB[4], blB[4];
    const size_t ba = ((size_t)(kcA * 4 + w) * 4) * 512 + (size_t)lane * 8;
    const size_t bbs = ((size_t)(kcB * 4 + w) * 4) * 512 + (size_t)lane * 8;
#pragma unroll
    for (int c = 0; c < 4; ++c) {
      bhA[c] = *(const f16x8*)&Bh[ba + c * 512];
      blA[c] = *(const f16x8*)&Bl[ba + c * 512];
      bhB[c] = *(const f16x8*)&Bh[bbs + c * 512];
      blB[c] = *(const f16x8*)&Bl[bbs + c * 512];
    }

#pragma unroll
    for (int rt = 0; rt < 4; ++rt) {
      const int nl = rt * 16 + lm;
      const int p0 = sP[nl], p1 = sP[nl + 1];
      float ava[8], avb[8];
#pragma unroll
      for (int j = 0; j < 8; ++j) { ava[j] = 0.f; avb[j] = 0.f; }
      for (int pos = p0; pos < p1; ++pos) {
        int src = useLds ? sSrc[pos - p0b] : srcs_s[pos];
        float ha = hA[(pos << 1) + klc];
        float hb = hB[(pos << 1) + klc];
        const float4* sp = (const float4*)(outn + (size_t)src * 64 + i0);
        float4 s0 = sp[0], s1 = sp[1];
        ava[0] += ha * s0.x; avb[0] += hb * s0.x;
        ava[1] += ha * s0.y; avb[1] += hb * s0.y;
        ava[2] += ha * s0.z; avb[2] += hb * s0.z;
        ava[3] += ha * s0.w; avb[3] += hb * s0.w;
        ava[4] += ha * s1.x; avb[4] += hb * s1.x;
        ava[5] += ha * s1.y; avb[5] += hb * s1.y;
        ava[6] += ha * s1.z; avb[6] += hb * s1.z;
        ava[7] += ha * s1.w; avb[7] += hb * s1.w;
      }
      const float inv = 1.f / (float)((p1 - p0) > 1 ? (p1 - p0) : 1);
#pragma unroll
      for (int j = 0; j < 8; ++j) { ava[j] *= inv; avb[j] *= inv; }
      f16x8 pha, pla, phb, plb;
      SPLIT16(ava, pha, pla);
      SPLIT16(avb, phb, plb);
#pragma unroll
      for (int c = 0; c < 4; ++c) {
        acc[rt][c] = __builtin_amdgcn_mfma_f32_16x16x32_f16(pha, bhA[c], acc[rt][c], 0, 0, 0);
        acc[rt][c] = __builtin_amdgcn_mfma_f32_16x16x32_f16(pha, blA[c], acc[rt][c], 0, 0, 0);
        acc[rt][c] = __builtin_amdgcn_mfma_f32_16x16x32_f16(pla, bhA[c], acc[rt][c], 0, 0, 0);
        acc[rt][c] = __builtin_amdgcn_mfma_f32_16x16x32_f16(phb, bhB[c], acc[rt][c], 0, 0, 0);
        acc[rt][c] = __builtin_amdgcn_mfma_f32_16x16x32_f16(phb, blB[c], acc[rt][c], 0, 0, 0);
        acc[rt][c] = __builtin_amdgcn_mfma_f32_16x16x32_f16(plb, bhB[c], acc[rt][c], 0, 0, 0);
      }
    }
  }

  // ---- tail: split 0 -> bias chunk (kc=64), split 1 -> root chunk (kc=65) --
  if (split < 2) {
    const int kc = 64 + split;
    f16x8 bh[4], bl[4];
    const size_t bt = ((size_t)(kc * 4 + w) * 4) * 512 + (size_t)lane * 8;
#pragma unroll
    for (int c = 0; c < 4; ++c) {
      bh[c] = *(const f16x8*)&Bh[bt + c * 512];
      bl[c] = *(const f16x8*)&Bl[bt + c * 512];
    }
#pragma unroll
    for (int rt = 0; rt < 4; ++rt) {
      const int nl = rt * 16 + lm;
      float av[8];
#pragma unroll
      for (int j = 0; j < 8; ++j) av[j] = 0.f;
      if (split == 0) {  // bias: A = sum_e 1 * s / deg, kl=0 half only
        if (klc == 0) {
          const int p0 = sP[nl], p1 = sP[nl + 1];
          for (int pos = p0; pos < p1; ++pos) {
            int src = useLds ? sSrc[pos - p0b] : srcs_s[pos];
            const float4* sp = (const float4*)(outn + (size_t)src * 64 + i0);
            float4 s0 = sp[0], s1 = sp[1];
            av[0] += s0.x; av[1] += s0.y; av[2] += s0.z; av[3] += s0.w;
            av[4] += s1.x; av[5] += s1.y; av[6] += s1.z; av[7] += s1.w;
          }
          const float inv = 1.f / (float)((p1 - p0) > 1 ? (p1 - p0) : 1);
#pragma unroll
          for (int j = 0; j < 8; ++j) av[j] *= inv;
        }
      } else {  // root: A = outn[n], kl=0 half only
        if (klc == 0 && n0 + nl < N) {
          const float4* sp = (const float4*)(outn + (size_t)(n0 + nl) * 64 + i0);
          float4 s0 = sp[0], s1 = sp[1];
          av[0] = s0.x; av[1] = s0.y; av[2] = s0.z; av[3] = s0.w;
          av[4] = s1.x; av[5] = s1.y; av[6] = s1.z; av[7] = s1.w;
        }
      }
      f16x8 ph, pl;
      SPLIT16(av, ph, pl);
#pragma unroll
      for (int c = 0; c < 4; ++c) {
        acc[rt][c] = __builtin_amdgcn_mfma_f32_16x16x32_f16(ph, bh[c], acc[rt][c], 0, 0, 0);
        acc[rt][c] = __builtin_amdgcn_mfma_f32_16x16x32_f16(ph, bl[c], acc[rt][c], 0, 0, 0);
        acc[rt][c] = __builtin_amdgcn_mfma_f32_16x16x32_f16(pl, bh[c], acc[rt][c], 0, 0, 0);
      }
    }
  }

  // ---- epilogue: atomic accumulate (split-K) ----
  const int qrow = (lane >> 4) * 4, col = lane & 15;
#pragma unroll
  for (int rt = 0; rt < 4; ++rt) {
#pragma unroll
    for (int r = 0; r < 4; ++r) {
      int nn = n0 + rt * 16 + qrow + r;
      if (nn < N) {
        float* ap = agg2 + (size_t)nn * 64 + col;
#pragma unroll
        for (int c = 0; c < 4; ++c) atomicAdd(ap + c * 16, acc[rt][c][r]);
      }
    }
  }
}

// GRU step (16 nodes/block, 4 per wave): m = relu(agg2+conv_b); out <- GRU
__global__ __launch_bounds__(256) void k_gru(
    const float* __restrict__ agg2, const float* __restrict__ conv_b,
    const float* __restrict__ gw_ih, const float* __restrict__ gw_hh,
    const float* __restrict__ gb_ih, const float* __restrict__ gb_hh,
    float* __restrict__ outn, int N) {
  __shared__ float wT[32 * 385];
  const int t = threadIdx.x;
  const int wv = t >> 6, d = t & 63;
  const int nbase = blockIdx.x * 16 + wv * 4;
  float m_d[4], h_d[4];
  bool act[4];
#pragma unroll
  for (int j = 0; j < 4; ++j) {
    int n = nbase + j;
    act[j] = (n < N);
    m_d[j] = act[j] ? fmaxf(agg2[(size_t)n * 64 + d] + conv_b[d], 0.f) : 0.f;
    h_d[j] = act[j] ? outn[(size_t)n * 64 + d] : 0.f;
  }
  float ir[4] = {0, 0, 0, 0}, iz[4] = {0, 0, 0, 0}, in_[4] = {0, 0, 0, 0};
  float hr[4] = {0, 0, 0, 0}, hz[4] = {0, 0, 0, 0}, hn[4] = {0, 0, 0, 0};
  for (int half = 0; half < 2; ++half) {
    __syncthreads();
    for (int idx = t; idx < 192 * 32; idx += 256) {
      int g = idx >> 5, kl = idx & 31;
      wT[kl * 385 + g] = gw_ih[g * 64 + half * 32 + kl];
      wT[kl * 385 + 192 + g] = gw_hh[g * 64 + half * 32 + kl];
    }
    __syncthreads();
#pragma unroll
    for (int kl = 0; kl < 32; ++kl) {
      int k = half * 32 + kl;
      const float* row = &wT[kl * 385];
      float r0 = row[d], r1 = row[64 + d], r2 = row[128 + d];
      float r3 = row[192 + d], r4 = row[256 + d], r5 = row[320 + d];
#pragma unroll
      for (int j = 0; j < 4; ++j) {
        float mk = __shfl(m_d[j], k);
        float hk = __shfl(h_d[j], k);
        ir[j] += r0 * mk;
        iz[j] += r1 * mk;
        in_[j] += r2 * mk;
        hr[j] += r3 * hk;
        hz[j] += r4 * hk;
        hn[j] += r5 * hk;
      }
    }
  }
#pragma unroll
  for (int j = 0; j < 4; ++j) {
    if (act[j]) {
      int n = nbase + j;
      float r = 1.f / (1.f + expf(-(ir[j] + gb_ih[d] + hr[j] + gb_hh[d])));
      float z = 1.f / (1.f + expf(-(iz[j] + gb_ih[64 + d] + hz[j] + gb_hh[64 + d])));
      float nn = tanhf(in_[j] + gb_ih[128 + d] + r * (hn[j] + gb_hh[128 + d]));
      outn[(size_t)n * 64 + d] = (1.f - z) * nn + z * h_d[j];
    }
  }
}

// Set2Set LSTM step
__global__ __launch_bounds__(256) void k_lstm(
    const float* __restrict__ w_ih, const float* __restrict__ w_hh,
    const float* __restrict__ b_ih, const float* __restrict__ b_hh,
    const float* __restrict__ qstar, float* __restrict__ hs,
    float* __restrict__ cs) {
  __shared__ float gate[256];
  __shared__ float q[128];
  __shared__ float h[64];
  const int b = blockIdx.x, t = threadIdx.x;
  if (t < 128) q[t] = qstar[b * 128 + t];
  if (t < 64) h[t] = hs[b * 64 + t];
  __syncthreads();
  float acc = b_ih[t] + b_hh[t];
  const float* wi = w_ih + t * 128;
  const float* wh = w_hh + t * 64;
#pragma unroll 4
  for (int k = 0; k < 128; ++k) acc += wi[k] * q[k];
#pragma unroll 4
  for (int k = 0; k < 64; ++k) acc += wh[k] * h[k];
  gate[t] = acc;
  __syncthreads();
  if (t < 64) {
    float ig = gate[t], fg = gate[64 + t], gg = gate[128 + t], og = gate[192 + t];
    float c = cs[b * 64 + t];
    float si = 1.f / (1.f + expf(-ig));
    float sf = 1.f / (1.f + expf(-fg));
    float so = 1.f / (1.f + expf(-og));
    float cn = sf * c + si * tanhf(gg);
    cs[b * 64 + t] = cn;
    hs[b * 64 + t] = so * tanhf(cn);
  }
}

// Set2Set attention: online softmax, single pass over segment
__global__ __launch_bounds__(64) void k_attn(const float* __restrict__ outn,
                                             const int* __restrict__ gptr,
                                             const float* __restrict__ hs,
                                             float* __restrict__ qstar) {
  const int b = blockIdx.x, d = threadIdx.x;
  const int n0 = gptr[b], n1 = gptr[b + 1];
  float qd = hs[b * 64 + d];
  float mx = -3.4e38f, den = 0.f, racc = 0.f;
  for (int n = n0; n < n1; ++n) {
    float od = outn[(size_t)n * 64 + d];
    float v = od * qd;
    for (int s = 32; s > 0; s >>= 1) v += __shfl_xor(v, s);
    float mnew = fmaxf(mx, v);
    float scale = expf(mx - mnew);  // first iter: exp(-inf) = 0
    float a = expf(v - mnew);
    den = den * scale + a;
    racc = racc * scale + a * od;
    mx = mnew;
  }
  float r = (den > 0.f) ? racc / den : 0.f;
  qstar[b * 128 + d] = qd;
  qstar[b * 128 + 64 + d] = r;
}

// readout
__global__ __launch_bounds__(64) void k_read(const float* __restrict__ qstar,
                                             const float* __restrict__ w1,
                                             const float* __restrict__ b1,
                                             const float* __restrict__ w2,
                                             const float* __restrict__ b2,
                                             float* __restrict__ y) {
  const int b = blockIdx.x, d = threadIdx.x;
  const float* q = qstar + b * 128;
  const float* wr = w1 + d * 128;
  float acc = b1[d];
#pragma unroll 4
  for (int k = 0; k < 128; ++k) acc += wr[k] * q[k];
  acc = fmaxf(acc, 0.f) * w2[d];
  for (int s = 32; s > 0; s >>= 1) acc += __shfl_xor(acc, s);
  if (d == 0) y[b] = acc + b2[0];
}

extern "C" void kernel_launch(void* const* d_in, const int* in_sizes, int n_in,
                              void* d_out, int out_size, void* d_ws,
                              size_t ws_size, hipStream_t stream) {
  (void)n_in; (void)out_size; (void)ws_size;
  const float* x      = (const float*)d_in[0];
  const int*   eidx   = (const int*)d_in[1];
  const float* eattr  = (const float*)d_in[2];
  const int*   batch  = (const int*)d_in[3];
  const float* lin0_w = (const float*)d_in[4];
  const float* lin0_b = (const float*)d_in[5];
  const float* nn1_w  = (const float*)d_in[6];
  const float* nn1_b  = (const float*)d_in[7];
  const float* nn2_w  = (const float*)d_in[8];
  const float* nn2_b  = (const float*)d_in[9];
  const float* root_w = (const float*)d_in[10];
  const float* conv_b = (const float*)d_in[11];
  const float* gw_ih  = (const float*)d_in[12];
  const float* gw_hh  = (const float*)d_in[13];
  const float* gb_ih  = (const float*)d_in[14];
  const float* gb_hh  = (const float*)d_in[15];
  const float* lw_ih  = (const float*)d_in[16];
  const float* lw_hh  = (const float*)d_in[17];
  const float* lb_ih  = (const float*)d_in[18];
  const float* lb_hh  = (const float*)d_in[19];
  const float* lin1_w = (const float*)d_in[20];
  const float* lin1_b = (const float*)d_in[21];
  const float* lin2_w = (const float*)d_in[22];
  const float* lin2_b = (const float*)d_in[23];

  const int N = in_sizes[0] / 11;
  const int E = in_sizes[1] / 2;
  const int B = 512;
  const int Epad = (E + 127) & ~127;

  size_t off = 0;
  auto bump = [&](size_t bytes) {
    size_t o = off;
    off += (bytes + 255) & ~(size_t)255;
    return o;
  };
  char* base = (char*)d_ws;
  float*     outn   = (float*)(base + bump((size_t)N * 64 * 4));
  float*     agg2   = (float*)(base + bump((size_t)N * 64 * 4));
  float2*    h1p    = (float2*)(base + bump((size_t)64 * Epad * 8));
  _Float16*  Bh     = (_Float16*)(base + bump((size_t)BFRAG_TOTAL * 2));
  _Float16*  Bl     = (_Float16*)(base + bump((size_t)BFRAG_TOTAL * 2));
  int*       cnt    = (int*)(base + bump((size_t)N * 4));
  int*       fill   = (int*)(base + bump((size_t)N * 4));
  int*       dptr   = (int*)(base + bump((size_t)(N + 1) * 4));
  int*       srcs_s = (int*)(base + bump((size_t)E * 4));
  int*       eord   = (int*)(base + bump((size_t)E * 4));
  float*     qstar  = (float*)(base + bump((size_t)B * 128 * 4));
  float*     hs     = (float*)(base + bump((size_t)B * 64 * 4));
  float*     cs     = (float*)(base + bump((size_t)B * 64 * 4));
  int*       gptr   = (int*)(base + bump((size_t)(B + 1) * 4));

  hipMemsetAsync(cnt, 0, (size_t)N * 4, stream);
  hipMemsetAsync(fill, 0, (size_t)N * 4, stream);
  hipMemsetAsync(qstar, 0, (size_t)B * 128 * 4, stream);
  hipMemsetAsync(hs, 0, (size_t)B * 64 * 4, stream);
  hipMemsetAsync(cs, 0, (size_t)B * 64 * 4, stream);

  k_gptr<<<(N + 255) / 256, 256, 0, stream>>>(batch, gptr, N, B);
  k_cnt<<<(E + 255) / 256, 256, 0, stream>>>(eidx, cnt, E);
  k_scan<<<1, 1024, 0, stream>>>(cnt, dptr, N);
  k_fill<<<(E + 255) / 256, 256, 0, stream>>>(eidx, dptr, fill, srcs_s, eord, E);
  k_h1t<<<(E + 127) / 128, 256, 0, stream>>>(eattr, eord, nn1_w, nn1_b, h1p, E,
                                             Epad);
  k_bsplit<<<(BFRAG_TOTAL + 255) / 256, 256, 0, stream>>>(nn2_w, nn2_b, root_w,
                                                          Bh, Bl);
  k_lin0<<<(N * 64 + 255) / 256, 256, 0, stream>>>(x, lin0_w, lin0_b, outn, N);

  const int NBLK = (N + 63) / 64;
  for (int it = 0; it < 3; ++it) {
    hipMemsetAsync(agg2, 0, (size_t)N * 64 * 4, stream);
    k_fused<<<dim3(NBLK, 4), 256, 0, stream>>>(outn, h1p, dptr, srcs_s, Bh, Bl,
                                               agg2, N, Epad);
    k_gru<<<(N + 15) / 16, 256, 0, stream>>>(agg2, conv_b, gw_ih, gw_hh, gb_ih,
                                             gb_hh, outn, N);
  }

  for (int s = 0; s < 3; ++s) {
    k_lstm<<<B, 256, 0, stream>>>(lw_ih, lw_hh, lb_ih, lb_hh, qstar, hs, cs);
    k_attn<<<B, 64, 0, stream>>>(outn, gptr, hs, qstar);
  }
  k_read<<<B, 64, 0, stream>>>(qstar, lin1_w, lin1_b, lin2_w, lin2_b,
                               (float*)d_out);
}

// Round 6
// 1258.680 us; speedup vs baseline: 1.2344x; 1.2344x over previous
//
#include <hip/hip_runtime.h>
#include <math.h>

// ---------------------------------------------------------------------------
// MPNN (NNConv+GRU x3, Set2Set x3, readout).
// R6: R4 structure (LDS A-staging, split-K x4) + block src-rows staged in LDS
// once (kills per-chunk L1 scatter re-gathers). M=32 node tile, 2 blocks/CU.
// 3-pass split-fp16 MFMA vs pre-split Wbig frags.
// ---------------------------------------------------------------------------

typedef _Float16 f16x8 __attribute__((ext_vector_type(8)));
typedef float f32x4 __attribute__((ext_vector_type(4)));

#define BFRAG_TOTAL (66 * 4 * 4 * 64 * 8)  // 540672 halves per array
#define SMAX 160                           // max edges per 32-node block (LDS)
#define SSTR 68                            // sRows row stride (floats, padded)

// graph segment pointers from sorted batch
__global__ void k_gptr(const int* __restrict__ batch, int* __restrict__ gptr,
                       int N, int B) {
  int n = blockIdx.x * 256 + threadIdx.x;
  if (n >= N) return;
  int b = batch[n];
  int bp = (n == 0) ? -1 : batch[n - 1];
  for (int g = bp + 1; g <= b; ++g) gptr[g] = n;
  if (n == N - 1) {
    for (int g = b + 1; g <= B; ++g) gptr[g] = N;
  }
}

__global__ void k_cnt(const int* __restrict__ eidx, int* __restrict__ cnt, int E) {
  int e = blockIdx.x * 256 + threadIdx.x;
  if (e < E) atomicAdd(&cnt[eidx[E + e]], 1);
}

// single-block scan via wave shuffles -> dptr (exclusive CSR pointers)
__global__ __launch_bounds__(1024) void k_scan(const int* __restrict__ cnt,
                                               int* __restrict__ dptr, int N) {
  __shared__ int wsum[16];
  int t = threadIdx.x;
  int lane = t & 63, wid = t >> 6;
  if (t == 0) dptr[0] = 0;
  int running = 0;
  for (int base = 0; base < N; base += 1024) {
    int x = (base + t < N) ? cnt[base + t] : 0;
#pragma unroll
    for (int d = 1; d < 64; d <<= 1) {
      int u = __shfl_up(x, d, 64);
      if (lane >= d) x += u;
    }
    if (lane == 63) wsum[wid] = x;
    __syncthreads();
    if (wid == 0) {
      int y = (lane < 16) ? wsum[lane] : 0;
#pragma unroll
      for (int d = 1; d < 16; d <<= 1) {
        int u = __shfl_up(y, d, 64);
        if (lane >= d) y += u;
      }
      if (lane < 16) wsum[lane] = y;
    }
    __syncthreads();
    int add = running + (wid > 0 ? wsum[wid - 1] : 0);
    if (base + t < N) dptr[base + t + 1] = add + x;
    running += wsum[15];
    __syncthreads();
  }
}

__global__ void k_fill(const int* __restrict__ eidx, const int* __restrict__ dptr,
                       int* __restrict__ fill, int* __restrict__ srcs_s,
                       int* __restrict__ eord, int E) {
  int e = blockIdx.x * 256 + threadIdx.x;
  if (e >= E) return;
  int d = eidx[E + e];
  int pos = dptr[d] + atomicAdd(&fill[d], 1);
  srcs_s[pos] = eidx[e];
  eord[pos] = e;
}

// h1p[k>>1][pos] = float2(h1[pos][2k'], h1[pos][2k'+1]) : k-major pair layout
__global__ __launch_bounds__(256) void k_h1t(const float* __restrict__ eattr,
                                             const int* __restrict__ eord,
                                             const float* __restrict__ nn1_w,
                                             const float* __restrict__ nn1_b,
                                             float2* __restrict__ h1p, int E,
                                             int Epad) {
  __shared__ float a5[128 * 5];
  __shared__ float w5[128 * 5];
  __shared__ float bb[128];
  const int t = threadIdx.x;
  const int p0 = blockIdx.x * 128;
  for (int idx = t; idx < 640; idx += 256) w5[idx] = nn1_w[idx];
  if (t < 128) bb[t] = nn1_b[t];
  if (t < 128) {
    int pos = p0 + t;
    if (pos < E) {
      int e = eord[pos];
      const float* a = eattr + (size_t)e * 5;
#pragma unroll
      for (int q = 0; q < 5; ++q) a5[t * 5 + q] = a[q];
    } else {
#pragma unroll
      for (int q = 0; q < 5; ++q) a5[t * 5 + q] = 0.f;
    }
  }
  __syncthreads();
  const int pl = t & 127, jh = (t >> 7) * 64;
  const int pos = p0 + pl;
  if (pos >= E) return;
  float a0 = a5[pl * 5 + 0], a1 = a5[pl * 5 + 1], a2 = a5[pl * 5 + 2],
        a3 = a5[pl * 5 + 3], a4 = a5[pl * 5 + 4];
#pragma unroll 8
  for (int jj = 0; jj < 64; jj += 2) {
    int j = jh + jj;
    const float* w0 = &w5[j * 5];
    float v0 = fmaxf(bb[j] + a0 * w0[0] + a1 * w0[1] + a2 * w0[2] + a3 * w0[3] +
                         a4 * w0[4], 0.f);
    const float* w1 = &w5[(j + 1) * 5];
    float v1 = fmaxf(bb[j + 1] + a0 * w1[0] + a1 * w1[1] + a2 * w1[2] +
                         a3 * w1[3] + a4 * w1[4], 0.f);
    h1p[(size_t)(j >> 1) * Epad + pos] = make_float2(v0, v1);
  }
}

// Pre-split Wbig into fp16 hi/lo in MFMA B-fragment order:
// flat idx = (((kc*4 + w)*4 + c)*64 + lane)*8 + j
__global__ void k_bsplit(const float* __restrict__ nn2_w,
                         const float* __restrict__ nn2_b,
                         const float* __restrict__ root_w,
                         _Float16* __restrict__ Bh, _Float16* __restrict__ Bl) {
  int idx = blockIdx.x * 256 + threadIdx.x;
  if (idx >= BFRAG_TOTAL) return;
  int j = idx & 7;
  int lane = (idx >> 3) & 63;
  int c = (idx >> 9) & 3;
  int w = (idx >> 11) & 3;
  int kc = idx >> 13;
  int m = w * 32 + ((lane >> 4) << 3) + j;
  int o = c * 16 + (lane & 15);
  int i = m & 63, kl = m >> 6;
  float v;
  if (kc < 64)
    v = nn2_w[(size_t)(i * 64 + o) * 128 + (kc * 2 + kl)];
  else if (kc == 64)
    v = (kl == 0) ? nn2_b[i * 64 + o] : 0.f;
  else
    v = (kl == 0) ? root_w[o * 64 + i] : 0.f;
  _Float16 h = (_Float16)v;
  Bh[idx] = h;
  Bl[idx] = (_Float16)(v - (float)h);
}

// out = relu(x @ lin0_w^T + lin0_b)
__global__ void k_lin0(const float* __restrict__ x, const float* __restrict__ w,
                       const float* __restrict__ b, float* __restrict__ outn, int N) {
  int gid = blockIdx.x * 256 + threadIdx.x;
  int n = gid >> 6, d = gid & 63;
  if (n >= N) return;
  const float* xr = x + (size_t)n * 11;
  const float* wr = w + d * 11;
  float acc = b[d];
#pragma unroll
  for (int f = 0; f < 11; ++f) acc += xr[f] * wr[f];
  outn[(size_t)n * 64 + d] = fmaxf(acc, 0.f);
}

// ---------------- fused NNConv (M=32 tile, src rows in LDS, split-K x4) ----
__global__ __launch_bounds__(256, 2) void k_fused(
    const float* __restrict__ outn, const float2* __restrict__ h1p,
    const int* __restrict__ dptr, const int* __restrict__ srcs_s,
    const _Float16* __restrict__ Bh, const _Float16* __restrict__ Bl,
    float* __restrict__ agg2, int N, int Epad) {
  __shared__ __align__(16) float sS[SMAX * SSTR];     // 43520 B src rows
  __shared__ __align__(16) _Float16 Ah[8 * 64 * 8];   // 8 KB
  __shared__ __align__(16) _Float16 Al[8 * 64 * 8];   // 8 KB
  __shared__ __align__(16) float2 hbuf[2][SMAX];      // 2.5 KB
  __shared__ int sP[33];

  const int t = threadIdx.x;
  const int w = t >> 6, lane = t & 63;
  const int nl = t >> 3;   // builder node (0..31)
  const int iq = t & 7;    // i-octet: cols iq*8..iq*8+7
  const int i0 = iq * 8;
  const int split = blockIdx.y;
  const int n0 = blockIdx.x * 32;

  if (t < 33) {
    int idx = n0 + t;
    sP[t] = dptr[idx > N ? N : idx];
  }
  __syncthreads();
  const int p0b = sP[0];
  const int EB = sP[32] - p0b;
  const bool useLds = (EB <= SMAX);
  const int EBs = useLds ? EB : 0;

  // ---- stage src rows (fp32) + first h chunk ----
  for (int idx = t; idx < EBs * 16; idx += 256) {
    int e = idx >> 4, q4 = idx & 15;
    int src = srcs_s[p0b + e];
    *(float4*)&sS[e * SSTR + q4 * 4] =
        *(const float4*)(outn + (size_t)src * 64 + q4 * 4);
  }
  {
    const float2* hc = h1p + (size_t)(split * 16) * Epad;
    for (int idx = t; idx < EBs; idx += 256) hbuf[0][idx] = hc[p0b + idx];
  }
  __syncthreads();

  const int p0 = sP[nl], p1 = sP[nl + 1];
  const float inv = 1.f / (float)((p1 - p0) > 1 ? (p1 - p0) : 1);
  const int rt_b = nl >> 4, lm = nl & 15;
  const int wb0 = iq >> 2, qq = iq & 3;  // m-block half + quad within it

  f32x4 acc[2][4];
#pragma unroll
  for (int a = 0; a < 2; ++a)
#pragma unroll
    for (int c = 0; c < 4; ++c) acc[a][c] = (f32x4)(0.f);

  const int niter = (split < 2) ? 17 : 16;
  int cur = 0;
  for (int cc = 0; cc < niter; ++cc) {
    const int mode = (cc < 16) ? 0 : ((split == 0) ? 1 : 2);
    const int kc = (cc < 16) ? (split * 16 + cc) : (64 + split);

    // ---- build this thread's 16 A-values (2 kl x 8 i) ----
    float av0[8], av1[8];
#pragma unroll
    for (int j = 0; j < 8; ++j) { av0[j] = 0.f; av1[j] = 0.f; }

    if (mode != 2) {
      const float2* hc = h1p + (size_t)kc * Epad;
      for (int pos = p0; pos < p1; ++pos) {
        int eoff = pos - p0b;
        float2 h;
        if (mode == 1) h = make_float2(1.f, 0.f);
        else h = useLds ? hbuf[cur][eoff] : hc[pos];
        float4 s0, s1;
        if (useLds) {
          s0 = *(const float4*)&sS[eoff * SSTR + i0];
          s1 = *(const float4*)&sS[eoff * SSTR + i0 + 4];
        } else {
          int src = srcs_s[pos];
          const float4* sp = (const float4*)(outn + (size_t)src * 64 + i0);
          s0 = sp[0]; s1 = sp[1];
        }
        av0[0] += h.x * s0.x; av1[0] += h.y * s0.x;
        av0[1] += h.x * s0.y; av1[1] += h.y * s0.y;
        av0[2] += h.x * s0.z; av1[2] += h.y * s0.z;
        av0[3] += h.x * s0.w; av1[3] += h.y * s0.w;
        av0[4] += h.x * s1.x; av1[4] += h.y * s1.x;
        av0[5] += h.x * s1.y; av1[5] += h.y * s1.y;
        av0[6] += h.x * s1.z; av1[6] += h.y * s1.z;
        av0[7] += h.x * s1.w; av1[7] += h.y * s1.w;
      }
#pragma unroll
      for (int j = 0; j < 8; ++j) { av0[j] *= inv; av1[j] *= inv; }
    } else {
      if (n0 + nl < N) {
        const float4* sp = (const float4*)(outn + (size_t)(n0 + nl) * 64 + i0);
        float4 s0 = sp[0], s1 = sp[1];
        av0[0] = s0.x; av0[1] = s0.y; av0[2] = s0.z; av0[3] = s0.w;
        av0[4] = s1.x; av0[5] = s1.y; av0[6] = s1.z; av0[7] = s1.w;
      }
    }

    // ---- split fp16 hi/lo, write A-frag order ----
#pragma unroll
    for (int kl = 0; kl < 2; ++kl) {
      const float* av = kl ? av1 : av0;
      int wg = kl * 2 + wb0;
      int base = ((wg * 2 + rt_b) * 64 + (qq << 4) + lm) * 8;
      f16x8 ph, pl;
#pragma unroll
      for (int jj = 0; jj < 8; ++jj) {
        float v = av[jj];
        _Float16 h = (_Float16)v;
        ph[jj] = h;
        pl[jj] = (_Float16)(v - (float)h);
      }
      *(f16x8*)&Ah[base] = ph;
      *(f16x8*)&Al[base] = pl;
    }
    __syncthreads();

    // ---- MFMA (wave w = m-slice) + prefetch next h chunk ----
    f16x8 ah[2], al[2];
#pragma unroll
    for (int rt = 0; rt < 2; ++rt) {
      ah[rt] = *(const f16x8*)&Ah[((w * 2 + rt) * 64 + lane) * 8];
      al[rt] = *(const f16x8*)&Al[((w * 2 + rt) * 64 + lane) * 8];
    }
    if (cc + 1 < 16) {
      const float2* hc = h1p + (size_t)(split * 16 + cc + 1) * Epad;
      for (int idx = t; idx < EBs; idx += 256) hbuf[cur ^ 1][idx] = hc[p0b + idx];
    }
    size_t bbase = ((size_t)(kc * 4 + w) * 4) * 512;
#pragma unroll
    for (int c = 0; c < 4; ++c) {
      f16x8 bh = *(const f16x8*)&Bh[bbase + c * 512 + lane * 8];
      f16x8 bl = *(const f16x8*)&Bl[bbase + c * 512 + lane * 8];
#pragma unroll
      for (int rt = 0; rt < 2; ++rt) {
        acc[rt][c] = __builtin_amdgcn_mfma_f32_16x16x32_f16(ah[rt], bh, acc[rt][c], 0, 0, 0);
        acc[rt][c] = __builtin_amdgcn_mfma_f32_16x16x32_f16(ah[rt], bl, acc[rt][c], 0, 0, 0);
        acc[rt][c] = __builtin_amdgcn_mfma_f32_16x16x32_f16(al[rt], bh, acc[rt][c], 0, 0, 0);
      }
    }
    __syncthreads();
    if (cc + 1 < 16) cur ^= 1;
  }

  // ---- epilogue: atomic accumulate (split-K) ----
  const int qrow = (lane >> 4) * 4, col = lane & 15;
#pragma unroll
  for (int rt = 0; rt < 2; ++rt) {
#pragma unroll
    for (int r = 0; r < 4; ++r) {
      int nn = n0 + rt * 16 + qrow + r;
      if (nn < N) {
        float* ap = agg2 + (size_t)nn * 64 + col;
#pragma unroll
        for (int c = 0; c < 4; ++c) atomicAdd(ap + c * 16, acc[rt][c][r]);
      }
    }
  }
}

// GRU step (16 nodes/block, 4 per wave): m = relu(agg2+conv_b); out <- GRU
__global__ __launch_bounds__(256) void k_gru(
    const float* __restrict__ agg2, const float* __restrict__ conv_b,
    const float* __restrict__ gw_ih, const float* __restrict__ gw_hh,
    const float* __restrict__ gb_ih, const float* __restrict__ gb_hh,
    float* __restrict__ outn, int N) {
  __shared__ float wT[32 * 385];
  const int t = threadIdx.x;
  const int wv = t >> 6, d = t & 63;
  const int nbase = blockIdx.x * 16 + wv * 4;
  float m_d[4], h_d[4];
  bool act[4];
#pragma unroll
  for (int j = 0; j < 4; ++j) {
    int n = nbase + j;
    act[j] = (n < N);
    m_d[j] = act[j] ? fmaxf(agg2[(size_t)n * 64 + d] + conv_b[d], 0.f) : 0.f;
    h_d[j] = act[j] ? outn[(size_t)n * 64 + d] : 0.f;
  }
  float ir[4] = {0, 0, 0, 0}, iz[4] = {0, 0, 0, 0}, in_[4] = {0, 0, 0, 0};
  float hr[4] = {0, 0, 0, 0}, hz[4] = {0, 0, 0, 0}, hn[4] = {0, 0, 0, 0};
  for (int half = 0; half < 2; ++half) {
    __syncthreads();
    for (int idx = t; idx < 192 * 32; idx += 256) {
      int g = idx >> 5, kl = idx & 31;
      wT[kl * 385 + g] = gw_ih[g * 64 + half * 32 + kl];
      wT[kl * 385 + 192 + g] = gw_hh[g * 64 + half * 32 + kl];
    }
    __syncthreads();
#pragma unroll
    for (int kl = 0; kl < 32; ++kl) {
      int k = half * 32 + kl;
      const float* row = &wT[kl * 385];
      float r0 = row[d], r1 = row[64 + d], r2 = row[128 + d];
      float r3 = row[192 + d], r4 = row[256 + d], r5 = row[320 + d];
#pragma unroll
      for (int j = 0; j < 4; ++j) {
        float mk = __shfl(m_d[j], k);
        float hk = __shfl(h_d[j], k);
        ir[j] += r0 * mk;
        iz[j] += r1 * mk;
        in_[j] += r2 * mk;
        hr[j] += r3 * hk;
        hz[j] += r4 * hk;
        hn[j] += r5 * hk;
      }
    }
  }
#pragma unroll
  for (int j = 0; j < 4; ++j) {
    if (act[j]) {
      int n = nbase + j;
      float r = 1.f / (1.f + expf(-(ir[j] + gb_ih[d] + hr[j] + gb_hh[d])));
      float z = 1.f / (1.f + expf(-(iz[j] + gb_ih[64 + d] + hz[j] + gb_hh[64 + d])));
      float nn = tanhf(in_[j] + gb_ih[128 + d] + r * (hn[j] + gb_hh[128 + d]));
      outn[(size_t)n * 64 + d] = (1.f - z) * nn + z * h_d[j];
    }
  }
}

// Set2Set LSTM step
__global__ __launch_bounds__(256) void k_lstm(
    const float* __restrict__ w_ih, const float* __restrict__ w_hh,
    const float* __restrict__ b_ih, const float* __restrict__ b_hh,
    const float* __restrict__ qstar, float* __restrict__ hs,
    float* __restrict__ cs) {
  __shared__ float gate[256];
  __shared__ float q[128];
  __shared__ float h[64];
  const int b = blockIdx.x, t = threadIdx.x;
  if (t < 128) q[t] = qstar[b * 128 + t];
  if (t < 64) h[t] = hs[b * 64 + t];
  __syncthreads();
  float acc = b_ih[t] + b_hh[t];
  const float* wi = w_ih + t * 128;
  const float* wh = w_hh + t * 64;
#pragma unroll 4
  for (int k = 0; k < 128; ++k) acc += wi[k] * q[k];
#pragma unroll 4
  for (int k = 0; k < 64; ++k) acc += wh[k] * h[k];
  gate[t] = acc;
  __syncthreads();
  if (t < 64) {
    float ig = gate[t], fg = gate[64 + t], gg = gate[128 + t], og = gate[192 + t];
    float c = cs[b * 64 + t];
    float si = 1.f / (1.f + expf(-ig));
    float sf = 1.f / (1.f + expf(-fg));
    float so = 1.f / (1.f + expf(-og));
    float cn = sf * c + si * tanhf(gg);
    cs[b * 64 + t] = cn;
    hs[b * 64 + t] = so * tanhf(cn);
  }
}

// Set2Set attention: online softmax, single pass over segment
__global__ __launch_bounds__(64) void k_attn(const float* __restrict__ outn,
                                             const int* __restrict__ gptr,
                                             const float* __restrict__ hs,
                                             float* __restrict__ qstar) {
  const int b = blockIdx.x, d = threadIdx.x;
  const int n0 = gptr[b], n1 = gptr[b + 1];
  float qd = hs[b * 64 + d];
  float mx = -3.4e38f, den = 0.f, racc = 0.f;
  for (int n = n0; n < n1; ++n) {
    float od = outn[(size_t)n * 64 + d];
    float v = od * qd;
    for (int s = 32; s > 0; s >>= 1) v += __shfl_xor(v, s);
    float mnew = fmaxf(mx, v);
    float scale = expf(mx - mnew);
    float a = expf(v - mnew);
    den = den * scale + a;
    racc = racc * scale + a * od;
    mx = mnew;
  }
  float r = (den > 0.f) ? racc / den : 0.f;
  qstar[b * 128 + d] = qd;
  qstar[b * 128 + 64 + d] = r;
}

// readout
__global__ __launch_bounds__(64) void k_read(const float* __restrict__ qstar,
                                             const float* __restrict__ w1,
                                             const float* __restrict__ b1,
                                             const float* __restrict__ w2,
                                             const float* __restrict__ b2,
                                             float* __restrict__ y) {
  const int b = blockIdx.x, d = threadIdx.x;
  const float* q = qstar + b * 128;
  const float* wr = w1 + d * 128;
  float acc = b1[d];
#pragma unroll 4
  for (int k = 0; k < 128; ++k) acc += wr[k] * q[k];
  acc = fmaxf(acc, 0.f) * w2[d];
  for (int s = 32; s > 0; s >>= 1) acc += __shfl_xor(acc, s);
  if (d == 0) y[b] = acc + b2[0];
}

extern "C" void kernel_launch(void* const* d_in, const int* in_sizes, int n_in,
                              void* d_out, int out_size, void* d_ws,
                              size_t ws_size, hipStream_t stream) {
  (void)n_in; (void)out_size; (void)ws_size;
  const float* x      = (const float*)d_in[0];
  const int*   eidx   = (const int*)d_in[1];
  const float* eattr  = (const float*)d_in[2];
  const int*   batch  = (const int*)d_in[3];
  const float* lin0_w = (const float*)d_in[4];
  const float* lin0_b = (const float*)d_in[5];
  const float* nn1_w  = (const float*)d_in[6];
  const float* nn1_b  = (const float*)d_in[7];
  const float* nn2_w  = (const float*)d_in[8];
  const float* nn2_b  = (const float*)d_in[9];
  const float* root_w = (const float*)d_in[10];
  const float* conv_b = (const float*)d_in[11];
  const float* gw_ih  = (const float*)d_in[12];
  const float* gw_hh  = (const float*)d_in[13];
  const float* gb_ih  = (const float*)d_in[14];
  const float* gb_hh  = (const float*)d_in[15];
  const float* lw_ih  = (const float*)d_in[16];
  const float* lw_hh  = (const float*)d_in[17];
  const float* lb_ih  = (const float*)d_in[18];
  const float* lb_hh  = (const float*)d_in[19];
  const float* lin1_w = (const float*)d_in[20];
  const float* lin1_b = (const float*)d_in[21];
  const float* lin2_w = (const float*)d_in[22];
  const float* lin2_b = (const float*)d_in[23];

  const int N = in_sizes[0] / 11;
  const int E = in_sizes[1] / 2;
  const int B = 512;
  const int Epad = (E + 127) & ~127;

  size_t off = 0;
  auto bump = [&](size_t bytes) {
    size_t o = off;
    off += (bytes + 255) & ~(size_t)255;
    return o;
  };
  char* base = (char*)d_ws;
  float*     outn   = (float*)(base + bump((size_t)N * 64 * 4));
  float*     agg2   = (float*)(base + bump((size_t)N * 64 * 4));
  float2*    h1p    = (float2*)(base + bump((size_t)64 * Epad * 8));
  _Float16*  Bh     = (_Float16*)(base + bump((size_t)BFRAG_TOTAL * 2));
  _Float16*  Bl     = (_Float16*)(base + bump((size_t)BFRAG_TOTAL * 2));
  int*       cnt    = (int*)(base + bump((size_t)N * 4));
  int*       fill   = (int*)(base + bump((size_t)N * 4));
  int*       dptr   = (int*)(base + bump((size_t)(N + 1) * 4));
  int*       srcs_s = (int*)(base + bump((size_t)E * 4));
  int*       eord   = (int*)(base + bump((size_t)E * 4));
  float*     qstar  = (float*)(base + bump((size_t)B * 128 * 4));
  float*     hs     = (float*)(base + bump((size_t)B * 64 * 4));
  float*     cs     = (float*)(base + bump((size_t)B * 64 * 4));
  int*       gptr   = (int*)(base + bump((size_t)(B + 1) * 4));

  hipMemsetAsync(cnt, 0, (size_t)N * 4, stream);
  hipMemsetAsync(fill, 0, (size_t)N * 4, stream);
  hipMemsetAsync(qstar, 0, (size_t)B * 128 * 4, stream);
  hipMemsetAsync(hs, 0, (size_t)B * 64 * 4, stream);
  hipMemsetAsync(cs, 0, (size_t)B * 64 * 4, stream);

  k_gptr<<<(N + 255) / 256, 256, 0, stream>>>(batch, gptr, N, B);
  k_cnt<<<(E + 255) / 256, 256, 0, stream>>>(eidx, cnt, E);
  k_scan<<<1, 1024, 0, stream>>>(cnt, dptr, N);
  k_fill<<<(E + 255) / 256, 256, 0, stream>>>(eidx, dptr, fill, srcs_s, eord, E);
  k_h1t<<<(E + 127) / 128, 256, 0, stream>>>(eattr, eord, nn1_w, nn1_b, h1p, E,
                                             Epad);
  k_bsplit<<<(BFRAG_TOTAL + 255) / 256, 256, 0, stream>>>(nn2_w, nn2_b, root_w,
                                                          Bh, Bl);
  k_lin0<<<(N * 64 + 255) / 256, 256, 0, stream>>>(x, lin0_w, lin0_b, outn, N);

  const int NBLK = (N + 31) / 32;
  for (int it = 0; it < 3; ++it) {
    hipMemsetAsync(agg2, 0, (size_t)N * 64 * 4, stream);
    k_fused<<<dim3(NBLK, 4), 256, 0, stream>>>(outn, h1p, dptr, srcs_s, Bh, Bl,
                                               agg2, N, Epad);
    k_gru<<<(N + 15) / 16, 256, 0, stream>>>(agg2, conv_b, gw_ih, gw_hh, gb_ih,
                                             gb_hh, outn, N);
  }

  for (int s = 0; s < 3; ++s) {
    k_lstm<<<B, 256, 0, stream>>>(lw_ih, lw_hh, lb_ih, lb_hh, qstar, hs, cs);
    k_attn<<<B, 64, 0, stream>>>(outn, gptr, hs, qstar);
  }
  k_read<<<B, 64, 0, stream>>>(qstar, lin1_w, lin1_b, lin2_w, lin2_b,
                               (float*)d_out);
}

// Round 8
// 1237.616 us; speedup vs baseline: 1.2554x; 1.0170x over previous
//
#include <hip/hip_runtime.h>
#include <math.h>

// ---------------------------------------------------------------------------
// MPNN (NNConv+GRU x3, Set2Set x3, readout).
// R8: R4 k_fused (M=64, LDS A-frags, split-K x4, atomicAdd epilogue) + B-frag
// hoist; fused Set2Set+readout (k_s2s). Workspace kept within R4's proven
// envelope (~44 MB) — R7's 4-slab agg overran ws_size and corrupted buffers.
// ---------------------------------------------------------------------------

typedef _Float16 f16x8 __attribute__((ext_vector_type(8)));
typedef float f32x4 __attribute__((ext_vector_type(4)));

#define BFRAG_TOTAL (66 * 4 * 4 * 64 * 8)  // 540672 halves per array
#define EMAXB 384                          // max edges per 64-node block (LDS)

// graph segment pointers from sorted batch
__global__ void k_gptr(const int* __restrict__ batch, int* __restrict__ gptr,
                       int N, int B) {
  int n = blockIdx.x * 256 + threadIdx.x;
  if (n >= N) return;
  int b = batch[n];
  int bp = (n == 0) ? -1 : batch[n - 1];
  for (int g = bp + 1; g <= b; ++g) gptr[g] = n;
  if (n == N - 1) {
    for (int g = b + 1; g <= B; ++g) gptr[g] = N;
  }
}

__global__ void k_cnt(const int* __restrict__ eidx, int* __restrict__ cnt, int E) {
  int e = blockIdx.x * 256 + threadIdx.x;
  if (e < E) atomicAdd(&cnt[eidx[E + e]], 1);
}

// single-block scan via wave shuffles -> dptr (exclusive CSR pointers)
__global__ __launch_bounds__(1024) void k_scan(const int* __restrict__ cnt,
                                               int* __restrict__ dptr, int N) {
  __shared__ int wsum[16];
  int t = threadIdx.x;
  int lane = t & 63, wid = t >> 6;
  if (t == 0) dptr[0] = 0;
  int running = 0;
  for (int base = 0; base < N; base += 1024) {
    int x = (base + t < N) ? cnt[base + t] : 0;
#pragma unroll
    for (int d = 1; d < 64; d <<= 1) {
      int u = __shfl_up(x, d, 64);
      if (lane >= d) x += u;
    }
    if (lane == 63) wsum[wid] = x;
    __syncthreads();
    if (wid == 0) {
      int y = (lane < 16) ? wsum[lane] : 0;
#pragma unroll
      for (int d = 1; d < 16; d <<= 1) {
        int u = __shfl_up(y, d, 64);
        if (lane >= d) y += u;
      }
      if (lane < 16) wsum[lane] = y;
    }
    __syncthreads();
    int add = running + (wid > 0 ? wsum[wid - 1] : 0);
    if (base + t < N) dptr[base + t + 1] = add + x;
    running += wsum[15];
    __syncthreads();
  }
}

__global__ void k_fill(const int* __restrict__ eidx, const int* __restrict__ dptr,
                       int* __restrict__ fill, int* __restrict__ srcs_s,
                       int* __restrict__ eord, int E) {
  int e = blockIdx.x * 256 + threadIdx.x;
  if (e >= E) return;
  int d = eidx[E + e];
  int pos = dptr[d] + atomicAdd(&fill[d], 1);
  srcs_s[pos] = eidx[e];
  eord[pos] = e;
}

// h1p[k>>1][pos] = float2(h1[pos][2k'], h1[pos][2k'+1]) : k-major pair layout
__global__ __launch_bounds__(256) void k_h1t(const float* __restrict__ eattr,
                                             const int* __restrict__ eord,
                                             const float* __restrict__ nn1_w,
                                             const float* __restrict__ nn1_b,
                                             float2* __restrict__ h1p, int E,
                                             int Epad) {
  __shared__ float a5[128 * 5];
  __shared__ float w5[128 * 5];
  __shared__ float bb[128];
  const int t = threadIdx.x;
  const int p0 = blockIdx.x * 128;
  for (int idx = t; idx < 640; idx += 256) w5[idx] = nn1_w[idx];
  if (t < 128) bb[t] = nn1_b[t];
  if (t < 128) {
    int pos = p0 + t;
    if (pos < E) {
      int e = eord[pos];
      const float* a = eattr + (size_t)e * 5;
#pragma unroll
      for (int q = 0; q < 5; ++q) a5[t * 5 + q] = a[q];
    } else {
#pragma unroll
      for (int q = 0; q < 5; ++q) a5[t * 5 + q] = 0.f;
    }
  }
  __syncthreads();
  const int pl = t & 127, jh = (t >> 7) * 64;
  const int pos = p0 + pl;
  if (pos >= E) return;
  float a0 = a5[pl * 5 + 0], a1 = a5[pl * 5 + 1], a2 = a5[pl * 5 + 2],
        a3 = a5[pl * 5 + 3], a4 = a5[pl * 5 + 4];
#pragma unroll 8
  for (int jj = 0; jj < 64; jj += 2) {
    int j = jh + jj;
    const float* w0 = &w5[j * 5];
    float v0 = fmaxf(bb[j] + a0 * w0[0] + a1 * w0[1] + a2 * w0[2] + a3 * w0[3] +
                         a4 * w0[4], 0.f);
    const float* w1 = &w5[(j + 1) * 5];
    float v1 = fmaxf(bb[j + 1] + a0 * w1[0] + a1 * w1[1] + a2 * w1[2] +
                         a3 * w1[3] + a4 * w1[4], 0.f);
    h1p[(size_t)(j >> 1) * Epad + pos] = make_float2(v0, v1);
  }
}

// Pre-split Wbig into fp16 hi/lo in MFMA B-fragment order:
// flat idx = (((kc*4 + w)*4 + c)*64 + lane)*8 + j
__global__ void k_bsplit(const float* __restrict__ nn2_w,
                         const float* __restrict__ nn2_b,
                         const float* __restrict__ root_w,
                         _Float16* __restrict__ Bh, _Float16* __restrict__ Bl) {
  int idx = blockIdx.x * 256 + threadIdx.x;
  if (idx >= BFRAG_TOTAL) return;
  int j = idx & 7;
  int lane = (idx >> 3) & 63;
  int c = (idx >> 9) & 3;
  int w = (idx >> 11) & 3;
  int kc = idx >> 13;
  int m = w * 32 + ((lane >> 4) << 3) + j;
  int o = c * 16 + (lane & 15);
  int i = m & 63, kl = m >> 6;
  float v;
  if (kc < 64)
    v = nn2_w[(size_t)(i * 64 + o) * 128 + (kc * 2 + kl)];
  else if (kc == 64)
    v = (kl == 0) ? nn2_b[i * 64 + o] : 0.f;
  else
    v = (kl == 0) ? root_w[o * 64 + i] : 0.f;
  _Float16 h = (_Float16)v;
  Bh[idx] = h;
  Bl[idx] = (_Float16)(v - (float)h);
}

// out = relu(x @ lin0_w^T + lin0_b)
__global__ void k_lin0(const float* __restrict__ x, const float* __restrict__ w,
                       const float* __restrict__ b, float* __restrict__ outn, int N) {
  int gid = blockIdx.x * 256 + threadIdx.x;
  int n = gid >> 6, d = gid & 63;
  if (n >= N) return;
  const float* xr = x + (size_t)n * 11;
  const float* wr = w + d * 11;
  float acc = b[d];
#pragma unroll
  for (int f = 0; f < 11; ++f) acc += xr[f] * wr[f];
  outn[(size_t)n * 64 + d] = fmaxf(acc, 0.f);
}

// ---------------- fused NNConv (M=64, LDS A-frags, split-K x4) -------------
__global__ __launch_bounds__(256, 3) void k_fused(
    const float* __restrict__ outn, const float2* __restrict__ h1p,
    const int* __restrict__ dptr, const int* __restrict__ srcs_s,
    const _Float16* __restrict__ Bh, const _Float16* __restrict__ Bl,
    float* __restrict__ agg2, int N, int Epad) {
  __shared__ __align__(16) _Float16 Ah[16 * 64 * 8];  // 16 KB
  __shared__ __align__(16) _Float16 Al[16 * 64 * 8];  // 16 KB
  __shared__ __align__(16) float2 hbuf[2][EMAXB];     // 6 KB
  __shared__ int sSrc[EMAXB];                         // 1.5 KB

  const int t = threadIdx.x;
  const int w = t >> 6, lane = t & 63;
  const int nl = t >> 2;   // builder node (0..63)
  const int iq = t & 3;    // i-quarter (16 cols)
  const int split = blockIdx.y;
  const int n0 = blockIdx.x * 64;
  const int n = n0 + nl;
  const bool nvalid = (n < N);
  const int hi_n = (n0 + 64 > N) ? N : (n0 + 64);
  const int p0b = dptr[n0];
  const int p1b = dptr[hi_n];
  const int EB = p1b - p0b;
  const bool useLds = (EB <= EMAXB);
  int p0 = 0, p1 = 0;
  if (nvalid) { p0 = dptr[n]; p1 = dptr[n + 1]; }
  const float inv = 1.f / (float)((p1 - p0) > 1 ? (p1 - p0) : 1);
  const int rt_b = nl >> 4, nm = nl & 15;
  const int EBs = useLds ? EB : 0;

  // ---- stage src list + first h chunk ----
  for (int idx = t; idx < EBs; idx += 256) sSrc[idx] = srcs_s[p0b + idx];
  {
    const float2* hc = h1p + (size_t)(split * 16) * Epad;
    for (int idx = t; idx < EBs; idx += 256) hbuf[0][idx] = hc[p0b + idx];
  }
  __syncthreads();

  f32x4 acc[4][4];
#pragma unroll
  for (int a = 0; a < 4; ++a)
#pragma unroll
    for (int c = 0; c < 4; ++c) acc[a][c] = (f32x4)(0.f);

  const int niter = (split < 2) ? 17 : 16;
  int cur = 0;
  for (int cc = 0; cc < niter; ++cc) {
    const int mode = (cc < 16) ? 0 : ((split == 0) ? 1 : 2);
    const int kc = (cc < 16) ? (split * 16 + cc) : (64 + split);

    // ---- hoist B frags (independent of barrier; latency overlaps A-build) --
    f16x8 bh[4], bl[4];
    {
      const size_t bbase = ((size_t)(kc * 4 + w) * 4) * 512 + (size_t)lane * 8;
#pragma unroll
      for (int c = 0; c < 4; ++c) {
        bh[c] = *(const f16x8*)&Bh[bbase + c * 512];
        bl[c] = *(const f16x8*)&Bl[bbase + c * 512];
      }
    }

    // ---- build this thread's 32 A-values (2 kl x 16 i) ----
    float av0[16], av1[16];
#pragma unroll
    for (int j = 0; j < 16; ++j) { av0[j] = 0.f; av1[j] = 0.f; }

    if (mode != 2) {
      const float2* hc = h1p + (size_t)kc * Epad;
      for (int pos = p0; pos < p1; ++pos) {
        float2 h;
        if (mode == 1) h = make_float2(1.f, 0.f);
        else h = useLds ? hbuf[cur][pos - p0b] : hc[pos];
        int src = useLds ? sSrc[pos - p0b] : srcs_s[pos];
        const float4* sp = (const float4*)(outn + (size_t)src * 64 + iq * 16);
        float4 s0 = sp[0], s1 = sp[1], s2 = sp[2], s3 = sp[3];
        float sv[16] = {s0.x, s0.y, s0.z, s0.w, s1.x, s1.y, s1.z, s1.w,
                        s2.x, s2.y, s2.z, s2.w, s3.x, s3.y, s3.z, s3.w};
#pragma unroll
        for (int j = 0; j < 16; ++j) {
          av0[j] += h.x * sv[j];
          av1[j] += h.y * sv[j];
        }
      }
#pragma unroll
      for (int j = 0; j < 16; ++j) { av0[j] *= inv; av1[j] *= inv; }
    } else {
      if (nvalid) {
        const float4* sp = (const float4*)(outn + (size_t)n * 64 + iq * 16);
        float4 s0 = sp[0], s1 = sp[1], s2 = sp[2], s3 = sp[3];
        float sv[16] = {s0.x, s0.y, s0.z, s0.w, s1.x, s1.y, s1.z, s1.w,
                        s2.x, s2.y, s2.z, s2.w, s3.x, s3.y, s3.z, s3.w};
#pragma unroll
        for (int j = 0; j < 16; ++j) av0[j] = sv[j];
      }
    }

    // ---- split fp16 hi/lo, write A-frag order ----
#pragma unroll
    for (int kl = 0; kl < 2; ++kl) {
      const float* av = kl ? av1 : av0;
      int wb = kl * 2 + (iq >> 1);
#pragma unroll
      for (int g = 0; g < 2; ++g) {
        int q = (iq & 1) * 2 + g;
        int base = ((wb * 4 + rt_b) * 64 + (q << 4) + nm) * 8;
        f16x8 ph, pl;
#pragma unroll
        for (int jj = 0; jj < 8; ++jj) {
          float v = av[g * 8 + jj];
          _Float16 h = (_Float16)v;
          ph[jj] = h;
          pl[jj] = (_Float16)(v - (float)h);
        }
        *(f16x8*)&Ah[base] = ph;
        *(f16x8*)&Al[base] = pl;
      }
    }
    __syncthreads();

    // ---- MFMA (wave w = k-slice) + prefetch next h chunk ----
    f16x8 ah[4], al[4];
#pragma unroll
    for (int rt = 0; rt < 4; ++rt) {
      ah[rt] = *(const f16x8*)&Ah[((w * 4 + rt) * 64 + lane) * 8];
      al[rt] = *(const f16x8*)&Al[((w * 4 + rt) * 64 + lane) * 8];
    }
    if (cc + 1 < 16) {
      const float2* hc = h1p + (size_t)(split * 16 + cc + 1) * Epad;
      for (int idx = t; idx < EBs; idx += 256) hbuf[cur ^ 1][idx] = hc[p0b + idx];
    }
#pragma unroll
    for (int c = 0; c < 4; ++c) {
#pragma unroll
      for (int rt = 0; rt < 4; ++rt) {
        acc[rt][c] = __builtin_amdgcn_mfma_f32_16x16x32_f16(ah[rt], bh[c], acc[rt][c], 0, 0, 0);
        acc[rt][c] = __builtin_amdgcn_mfma_f32_16x16x32_f16(ah[rt], bl[c], acc[rt][c], 0, 0, 0);
        acc[rt][c] = __builtin_amdgcn_mfma_f32_16x16x32_f16(al[rt], bh[c], acc[rt][c], 0, 0, 0);
      }
    }
    __syncthreads();
    if (cc + 1 < 16) cur ^= 1;
  }

  // ---- epilogue: atomic accumulate (split-K) ----
  const int qrow = (lane >> 4) * 4, col = lane & 15;
#pragma unroll
  for (int rt = 0; rt < 4; ++rt) {
#pragma unroll
    for (int r = 0; r < 4; ++r) {
      int nn = n0 + rt * 16 + qrow + r;
      if (nn < N) {
        float* ap = agg2 + (size_t)nn * 64 + col;
#pragma unroll
        for (int c = 0; c < 4; ++c) atomicAdd(ap + c * 16, acc[rt][c][r]);
      }
    }
  }
}

// GRU step (16 nodes/block, 4 per wave): m = relu(agg2+conv_b); out <- GRU
__global__ __launch_bounds__(256) void k_gru(
    const float* __restrict__ agg2, const float* __restrict__ conv_b,
    const float* __restrict__ gw_ih, const float* __restrict__ gw_hh,
    const float* __restrict__ gb_ih, const float* __restrict__ gb_hh,
    float* __restrict__ outn, int N) {
  __shared__ float wT[32 * 385];
  const int t = threadIdx.x;
  const int wv = t >> 6, d = t & 63;
  const int nbase = blockIdx.x * 16 + wv * 4;
  float m_d[4], h_d[4];
  bool act[4];
#pragma unroll
  for (int j = 0; j < 4; ++j) {
    int n = nbase + j;
    act[j] = (n < N);
    m_d[j] = act[j] ? fmaxf(agg2[(size_t)n * 64 + d] + conv_b[d], 0.f) : 0.f;
    h_d[j] = act[j] ? outn[(size_t)n * 64 + d] : 0.f;
  }
  float ir[4] = {0, 0, 0, 0}, iz[4] = {0, 0, 0, 0}, in_[4] = {0, 0, 0, 0};
  float hr[4] = {0, 0, 0, 0}, hz[4] = {0, 0, 0, 0}, hn[4] = {0, 0, 0, 0};
  for (int half = 0; half < 2; ++half) {
    __syncthreads();
    for (int idx = t; idx < 192 * 32; idx += 256) {
      int g = idx >> 5, kl = idx & 31;
      wT[kl * 385 + g] = gw_ih[g * 64 + half * 32 + kl];
      wT[kl * 385 + 192 + g] = gw_hh[g * 64 + half * 32 + kl];
    }
    __syncthreads();
#pragma unroll
    for (int kl = 0; kl < 32; ++kl) {
      int k = half * 32 + kl;
      const float* row = &wT[kl * 385];
      float r0 = row[d], r1 = row[64 + d], r2 = row[128 + d];
      float r3 = row[192 + d], r4 = row[256 + d], r5 = row[320 + d];
#pragma unroll
      for (int j = 0; j < 4; ++j) {
        float mk = __shfl(m_d[j], k);
        float hk = __shfl(h_d[j], k);
        ir[j] += r0 * mk;
        iz[j] += r1 * mk;
        in_[j] += r2 * mk;
        hr[j] += r3 * hk;
        hz[j] += r4 * hk;
        hn[j] += r5 * hk;
      }
    }
  }
#pragma unroll
  for (int j = 0; j < 4; ++j) {
    if (act[j]) {
      int n = nbase + j;
      float r = 1.f / (1.f + expf(-(ir[j] + gb_ih[d] + hr[j] + gb_hh[d])));
      float z = 1.f / (1.f + expf(-(iz[j] + gb_ih[64 + d] + hz[j] + gb_hh[64 + d])));
      float nn = tanhf(in_[j] + gb_ih[128 + d] + r * (hn[j] + gb_hh[128 + d]));
      outn[(size_t)n * 64 + d] = (1.f - z) * nn + z * h_d[j];
    }
  }
}

// ---------------- fused Set2Set (3 steps) + readout, one block per graph ---
__global__ __launch_bounds__(256) void k_s2s(
    const float* __restrict__ outn, const int* __restrict__ gptr,
    const float* __restrict__ w_ih, const float* __restrict__ w_hh,
    const float* __restrict__ b_ih, const float* __restrict__ b_hh,
    const float* __restrict__ w1, const float* __restrict__ b1,
    const float* __restrict__ w2, const float* __restrict__ b2,
    float* __restrict__ y) {
  __shared__ float q[128];
  __shared__ float hsL[64];
  __shared__ float csL[64];
  __shared__ float gate[256];
  __shared__ float red[4][66];  // per-wave: m, den, racc[64]
  const int b = blockIdx.x, t = threadIdx.x;
  const int wv = t >> 6, d = t & 63;
  const int n0 = gptr[b], n1 = gptr[b + 1];
  if (t < 128) q[t] = 0.f;
  if (t < 64) { hsL[t] = 0.f; csL[t] = 0.f; }
  __syncthreads();

  for (int step = 0; step < 3; ++step) {
    // LSTM gates: 256 threads = 256 gate units
    float acc = b_ih[t] + b_hh[t];
    const float* wi = w_ih + t * 128;
    const float* wh = w_hh + t * 64;
#pragma unroll 4
    for (int k = 0; k < 128; ++k) acc += wi[k] * q[k];
#pragma unroll 4
    for (int k = 0; k < 64; ++k) acc += wh[k] * hsL[k];
    gate[t] = acc;
    __syncthreads();
    if (t < 64) {
      float ig = gate[t], fg = gate[64 + t], gg = gate[128 + t],
            og = gate[192 + t];
      float c = csL[t];
      float si = 1.f / (1.f + expf(-ig));
      float sf = 1.f / (1.f + expf(-fg));
      float so = 1.f / (1.f + expf(-og));
      float cn = sf * c + si * tanhf(gg);
      csL[t] = cn;
      hsL[t] = so * tanhf(cn);
    }
    __syncthreads();

    // attention: wave wv handles nodes n0+wv, n0+wv+4, ... (online softmax)
    float qd = hsL[d];
    float mx = -3.4e38f, den = 0.f, racc = 0.f;
    for (int nn = n0 + wv; nn < n1; nn += 4) {
      float od = outn[(size_t)nn * 64 + d];
      float v = od * qd;
      for (int s = 32; s > 0; s >>= 1) v += __shfl_xor(v, s);
      float mnew = fmaxf(mx, v);
      float scale = expf(mx - mnew);
      float a = expf(v - mnew);
      den = den * scale + a;
      racc = racc * scale + a * od;
      mx = mnew;
    }
    if (d == 0) { red[wv][0] = mx; red[wv][1] = den; }
    red[wv][2 + d] = racc;
    __syncthreads();
    if (t < 64) {
      float M = fmaxf(fmaxf(red[0][0], red[1][0]), fmaxf(red[2][0], red[3][0]));
      float dd = 0.f, rr = 0.f;
#pragma unroll
      for (int ww = 0; ww < 4; ++ww) {
        float sc = expf(red[ww][0] - M);
        dd += red[ww][1] * sc;
        rr += red[ww][2 + t] * sc;
      }
      float r = (dd > 0.f) ? rr / dd : 0.f;
      q[t] = hsL[t];
      q[64 + t] = r;
    }
    __syncthreads();
  }

  // readout: y[b] = relu(q @ lin1^T + b1) @ lin2^T + b2
  if (t < 64) {
    float acc = b1[t];
    const float* wr = w1 + t * 128;
#pragma unroll 4
    for (int k = 0; k < 128; ++k) acc += wr[k] * q[k];
    acc = fmaxf(acc, 0.f) * w2[t];
    for (int s = 32; s > 0; s >>= 1) acc += __shfl_xor(acc, s);
    if (t == 0) y[b] = acc + b2[0];
  }
}

extern "C" void kernel_launch(void* const* d_in, const int* in_sizes, int n_in,
                              void* d_out, int out_size, void* d_ws,
                              size_t ws_size, hipStream_t stream) {
  (void)n_in; (void)out_size; (void)ws_size;
  const float* x      = (const float*)d_in[0];
  const int*   eidx   = (const int*)d_in[1];
  const float* eattr  = (const float*)d_in[2];
  const int*   batch  = (const int*)d_in[3];
  const float* lin0_w = (const float*)d_in[4];
  const float* lin0_b = (const float*)d_in[5];
  const float* nn1_w  = (const float*)d_in[6];
  const float* nn1_b  = (const float*)d_in[7];
  const float* nn2_w  = (const float*)d_in[8];
  const float* nn2_b  = (const float*)d_in[9];
  const float* root_w = (const float*)d_in[10];
  const float* conv_b = (const float*)d_in[11];
  const float* gw_ih  = (const float*)d_in[12];
  const float* gw_hh  = (const float*)d_in[13];
  const float* gb_ih  = (const float*)d_in[14];
  const float* gb_hh  = (const float*)d_in[15];
  const float* lw_ih  = (const float*)d_in[16];
  const float* lw_hh  = (const float*)d_in[17];
  const float* lb_ih  = (const float*)d_in[18];
  const float* lb_hh  = (const float*)d_in[19];
  const float* lin1_w = (const float*)d_in[20];
  const float* lin1_b = (const float*)d_in[21];
  const float* lin2_w = (const float*)d_in[22];
  const float* lin2_b = (const float*)d_in[23];

  const int N = in_sizes[0] / 11;
  const int E = in_sizes[1] / 2;
  const int B = 512;
  const int Epad = (E + 127) & ~127;

  size_t off = 0;
  auto bump = [&](size_t bytes) {
    size_t o = off;
    off += (bytes + 255) & ~(size_t)255;
    return o;
  };
  char* base = (char*)d_ws;
  float*     outn   = (float*)(base + bump((size_t)N * 64 * 4));
  float*     agg2   = (float*)(base + bump((size_t)N * 64 * 4));
  float2*    h1p    = (float2*)(base + bump((size_t)64 * Epad * 8));
  _Float16*  Bh     = (_Float16*)(base + bump((size_t)BFRAG_TOTAL * 2));
  _Float16*  Bl     = (_Float16*)(base + bump((size_t)BFRAG_TOTAL * 2));
  int*       cnt    = (int*)(base + bump((size_t)2 * N * 4));  // cnt + fill
  int*       fill   = cnt + N;
  int*       dptr   = (int*)(base + bump((size_t)(N + 1) * 4));
  int*       srcs_s = (int*)(base + bump((size_t)E * 4));
  int*       eord   = (int*)(base + bump((size_t)E * 4));
  int*       gptr   = (int*)(base + bump((size_t)(B + 1) * 4));

  hipMemsetAsync(cnt, 0, (size_t)2 * N * 4, stream);

  k_gptr<<<(N + 255) / 256, 256, 0, stream>>>(batch, gptr, N, B);
  k_cnt<<<(E + 255) / 256, 256, 0, stream>>>(eidx, cnt, E);
  k_scan<<<1, 1024, 0, stream>>>(cnt, dptr, N);
  k_fill<<<(E + 255) / 256, 256, 0, stream>>>(eidx, dptr, fill, srcs_s, eord, E);
  k_h1t<<<(E + 127) / 128, 256, 0, stream>>>(eattr, eord, nn1_w, nn1_b, h1p, E,
                                             Epad);
  k_bsplit<<<(BFRAG_TOTAL + 255) / 256, 256, 0, stream>>>(nn2_w, nn2_b, root_w,
                                                          Bh, Bl);
  k_lin0<<<(N * 64 + 255) / 256, 256, 0, stream>>>(x, lin0_w, lin0_b, outn, N);

  const int NBLK = (N + 63) / 64;
  for (int it = 0; it < 3; ++it) {
    hipMemsetAsync(agg2, 0, (size_t)N * 64 * 4, stream);
    k_fused<<<dim3(NBLK, 4), 256, 0, stream>>>(outn, h1p, dptr, srcs_s, Bh, Bl,
                                               agg2, N, Epad);
    k_gru<<<(N + 15) / 16, 256, 0, stream>>>(agg2, conv_b, gw_ih, gw_hh, gb_ih,
                                             gb_hh, outn, N);
  }

  k_s2s<<<B, 256, 0, stream>>>(outn, gptr, lw_ih, lw_hh, lb_ih, lb_hh, lin1_w,
                               lin1_b, lin2_w, lin2_b, (float*)d_out);
}

// Round 9
// 1136.814 us; speedup vs baseline: 1.3667x; 1.0887x over previous
//
#include <hip/hip_runtime.h>
#include <math.h>

// ---------------------------------------------------------------------------
// MPNN (NNConv+GRU x3, Set2Set x3, readout).
// R9: R4 k_fused exactly (M=64, LDS A-frags, B-frags loaded in MFMA phase —
// R8's hoist caused scratch spills), split-K x8 for occupancy; fused
// Set2Set+readout (k_s2s). Workspace within R4's proven envelope.
// ---------------------------------------------------------------------------

typedef _Float16 f16x8 __attribute__((ext_vector_type(8)));
typedef float f32x4 __attribute__((ext_vector_type(4)));

#define BFRAG_TOTAL (66 * 4 * 4 * 64 * 8)  // 540672 halves per array
#define EMAXB 384                          // max edges per 64-node block (LDS)
#define SPLITK 8
#define CPS 8                              // chunks per split (64/SPLITK)

// graph segment pointers from sorted batch
__global__ void k_gptr(const int* __restrict__ batch, int* __restrict__ gptr,
                       int N, int B) {
  int n = blockIdx.x * 256 + threadIdx.x;
  if (n >= N) return;
  int b = batch[n];
  int bp = (n == 0) ? -1 : batch[n - 1];
  for (int g = bp + 1; g <= b; ++g) gptr[g] = n;
  if (n == N - 1) {
    for (int g = b + 1; g <= B; ++g) gptr[g] = N;
  }
}

__global__ void k_cnt(const int* __restrict__ eidx, int* __restrict__ cnt, int E) {
  int e = blockIdx.x * 256 + threadIdx.x;
  if (e < E) atomicAdd(&cnt[eidx[E + e]], 1);
}

// single-block scan via wave shuffles -> dptr (exclusive CSR pointers)
__global__ __launch_bounds__(1024) void k_scan(const int* __restrict__ cnt,
                                               int* __restrict__ dptr, int N) {
  __shared__ int wsum[16];
  int t = threadIdx.x;
  int lane = t & 63, wid = t >> 6;
  if (t == 0) dptr[0] = 0;
  int running = 0;
  for (int base = 0; base < N; base += 1024) {
    int x = (base + t < N) ? cnt[base + t] : 0;
#pragma unroll
    for (int d = 1; d < 64; d <<= 1) {
      int u = __shfl_up(x, d, 64);
      if (lane >= d) x += u;
    }
    if (lane == 63) wsum[wid] = x;
    __syncthreads();
    if (wid == 0) {
      int y = (lane < 16) ? wsum[lane] : 0;
#pragma unroll
      for (int d = 1; d < 16; d <<= 1) {
        int u = __shfl_up(y, d, 64);
        if (lane >= d) y += u;
      }
      if (lane < 16) wsum[lane] = y;
    }
    __syncthreads();
    int add = running + (wid > 0 ? wsum[wid - 1] : 0);
    if (base + t < N) dptr[base + t + 1] = add + x;
    running += wsum[15];
    __syncthreads();
  }
}

__global__ void k_fill(const int* __restrict__ eidx, const int* __restrict__ dptr,
                       int* __restrict__ fill, int* __restrict__ srcs_s,
                       int* __restrict__ eord, int E) {
  int e = blockIdx.x * 256 + threadIdx.x;
  if (e >= E) return;
  int d = eidx[E + e];
  int pos = dptr[d] + atomicAdd(&fill[d], 1);
  srcs_s[pos] = eidx[e];
  eord[pos] = e;
}

// h1p[k>>1][pos] = float2(h1[pos][2k'], h1[pos][2k'+1]) : k-major pair layout
__global__ __launch_bounds__(256) void k_h1t(const float* __restrict__ eattr,
                                             const int* __restrict__ eord,
                                             const float* __restrict__ nn1_w,
                                             const float* __restrict__ nn1_b,
                                             float2* __restrict__ h1p, int E,
                                             int Epad) {
  __shared__ float a5[128 * 5];
  __shared__ float w5[128 * 5];
  __shared__ float bb[128];
  const int t = threadIdx.x;
  const int p0 = blockIdx.x * 128;
  for (int idx = t; idx < 640; idx += 256) w5[idx] = nn1_w[idx];
  if (t < 128) bb[t] = nn1_b[t];
  if (t < 128) {
    int pos = p0 + t;
    if (pos < E) {
      int e = eord[pos];
      const float* a = eattr + (size_t)e * 5;
#pragma unroll
      for (int q = 0; q < 5; ++q) a5[t * 5 + q] = a[q];
    } else {
#pragma unroll
      for (int q = 0; q < 5; ++q) a5[t * 5 + q] = 0.f;
    }
  }
  __syncthreads();
  const int pl = t & 127, jh = (t >> 7) * 64;
  const int pos = p0 + pl;
  if (pos >= E) return;
  float a0 = a5[pl * 5 + 0], a1 = a5[pl * 5 + 1], a2 = a5[pl * 5 + 2],
        a3 = a5[pl * 5 + 3], a4 = a5[pl * 5 + 4];
#pragma unroll 8
  for (int jj = 0; jj < 64; jj += 2) {
    int j = jh + jj;
    const float* w0 = &w5[j * 5];
    float v0 = fmaxf(bb[j] + a0 * w0[0] + a1 * w0[1] + a2 * w0[2] + a3 * w0[3] +
                         a4 * w0[4], 0.f);
    const float* w1 = &w5[(j + 1) * 5];
    float v1 = fmaxf(bb[j + 1] + a0 * w1[0] + a1 * w1[1] + a2 * w1[2] +
                         a3 * w1[3] + a4 * w1[4], 0.f);
    h1p[(size_t)(j >> 1) * Epad + pos] = make_float2(v0, v1);
  }
}

// Pre-split Wbig into fp16 hi/lo in MFMA B-fragment order:
// flat idx = (((kc*4 + w)*4 + c)*64 + lane)*8 + j
__global__ void k_bsplit(const float* __restrict__ nn2_w,
                         const float* __restrict__ nn2_b,
                         const float* __restrict__ root_w,
                         _Float16* __restrict__ Bh, _Float16* __restrict__ Bl) {
  int idx = blockIdx.x * 256 + threadIdx.x;
  if (idx >= BFRAG_TOTAL) return;
  int j = idx & 7;
  int lane = (idx >> 3) & 63;
  int c = (idx >> 9) & 3;
  int w = (idx >> 11) & 3;
  int kc = idx >> 13;
  int m = w * 32 + ((lane >> 4) << 3) + j;
  int o = c * 16 + (lane & 15);
  int i = m & 63, kl = m >> 6;
  float v;
  if (kc < 64)
    v = nn2_w[(size_t)(i * 64 + o) * 128 + (kc * 2 + kl)];
  else if (kc == 64)
    v = (kl == 0) ? nn2_b[i * 64 + o] : 0.f;
  else
    v = (kl == 0) ? root_w[o * 64 + i] : 0.f;
  _Float16 h = (_Float16)v;
  Bh[idx] = h;
  Bl[idx] = (_Float16)(v - (float)h);
}

// out = relu(x @ lin0_w^T + lin0_b)
__global__ void k_lin0(const float* __restrict__ x, const float* __restrict__ w,
                       const float* __restrict__ b, float* __restrict__ outn, int N) {
  int gid = blockIdx.x * 256 + threadIdx.x;
  int n = gid >> 6, d = gid & 63;
  if (n >= N) return;
  const float* xr = x + (size_t)n * 11;
  const float* wr = w + d * 11;
  float acc = b[d];
#pragma unroll
  for (int f = 0; f < 11; ++f) acc += xr[f] * wr[f];
  outn[(size_t)n * 64 + d] = fmaxf(acc, 0.f);
}

// ---------------- fused NNConv (M=64, LDS A-frags, split-K x8) -------------
__global__ __launch_bounds__(256, 3) void k_fused(
    const float* __restrict__ outn, const float2* __restrict__ h1p,
    const int* __restrict__ dptr, const int* __restrict__ srcs_s,
    const _Float16* __restrict__ Bh, const _Float16* __restrict__ Bl,
    float* __restrict__ agg2, int N, int Epad) {
  __shared__ __align__(16) _Float16 Ah[16 * 64 * 8];  // 16 KB
  __shared__ __align__(16) _Float16 Al[16 * 64 * 8];  // 16 KB
  __shared__ __align__(16) float2 hbuf[2][EMAXB];     // 6 KB
  __shared__ int sSrc[EMAXB];                         // 1.5 KB

  const int t = threadIdx.x;
  const int w = t >> 6, lane = t & 63;
  const int nl = t >> 2;   // builder node (0..63)
  const int iq = t & 3;    // i-quarter (16 cols)
  const int split = blockIdx.y;
  const int n0 = blockIdx.x * 64;
  const int n = n0 + nl;
  const bool nvalid = (n < N);
  const int hi_n = (n0 + 64 > N) ? N : (n0 + 64);
  const int p0b = dptr[n0];
  const int p1b = dptr[hi_n];
  const int EB = p1b - p0b;
  const bool useLds = (EB <= EMAXB);
  int p0 = 0, p1 = 0;
  if (nvalid) { p0 = dptr[n]; p1 = dptr[n + 1]; }
  const float inv = 1.f / (float)((p1 - p0) > 1 ? (p1 - p0) : 1);
  const int rt_b = nl >> 4, nm = nl & 15;
  const int EBs = useLds ? EB : 0;

  // ---- stage src list + first h chunk ----
  for (int idx = t; idx < EBs; idx += 256) sSrc[idx] = srcs_s[p0b + idx];
  {
    const float2* hc = h1p + (size_t)(split * CPS) * Epad;
    for (int idx = t; idx < EBs; idx += 256) hbuf[0][idx] = hc[p0b + idx];
  }
  __syncthreads();

  f32x4 acc[4][4];
#pragma unroll
  for (int a = 0; a < 4; ++a)
#pragma unroll
    for (int c = 0; c < 4; ++c) acc[a][c] = (f32x4)(0.f);

  const int niter = (split < 2) ? (CPS + 1) : CPS;
  int cur = 0;
  for (int cc = 0; cc < niter; ++cc) {
    const int mode = (cc < CPS) ? 0 : ((split == 0) ? 1 : 2);
    const int kc = (cc < CPS) ? (split * CPS + cc) : (64 + split);

    // ---- build this thread's 32 A-values (2 kl x 16 i) ----
    float av0[16], av1[16];
#pragma unroll
    for (int j = 0; j < 16; ++j) { av0[j] = 0.f; av1[j] = 0.f; }

    if (mode != 2) {
      const float2* hc = h1p + (size_t)kc * Epad;
      for (int pos = p0; pos < p1; ++pos) {
        float2 h;
        if (mode == 1) h = make_float2(1.f, 0.f);
        else h = useLds ? hbuf[cur][pos - p0b] : hc[pos];
        int src = useLds ? sSrc[pos - p0b] : srcs_s[pos];
        const float4* sp = (const float4*)(outn + (size_t)src * 64 + iq * 16);
        float4 s0 = sp[0], s1 = sp[1], s2 = sp[2], s3 = sp[3];
        float sv[16] = {s0.x, s0.y, s0.z, s0.w, s1.x, s1.y, s1.z, s1.w,
                        s2.x, s2.y, s2.z, s2.w, s3.x, s3.y, s3.z, s3.w};
#pragma unroll
        for (int j = 0; j < 16; ++j) {
          av0[j] += h.x * sv[j];
          av1[j] += h.y * sv[j];
        }
      }
#pragma unroll
      for (int j = 0; j < 16; ++j) { av0[j] *= inv; av1[j] *= inv; }
    } else {
      if (nvalid) {
        const float4* sp = (const float4*)(outn + (size_t)n * 64 + iq * 16);
        float4 s0 = sp[0], s1 = sp[1], s2 = sp[2], s3 = sp[3];
        float sv[16] = {s0.x, s0.y, s0.z, s0.w, s1.x, s1.y, s1.z, s1.w,
                        s2.x, s2.y, s2.z, s2.w, s3.x, s3.y, s3.z, s3.w};
#pragma unroll
        for (int j = 0; j < 16; ++j) av0[j] = sv[j];
      }
    }

    // ---- split fp16 hi/lo, write A-frag order ----
#pragma unroll
    for (int kl = 0; kl < 2; ++kl) {
      const float* av = kl ? av1 : av0;
      int wb = kl * 2 + (iq >> 1);
#pragma unroll
      for (int g = 0; g < 2; ++g) {
        int q = (iq & 1) * 2 + g;
        int base = ((wb * 4 + rt_b) * 64 + (q << 4) + nm) * 8;
        f16x8 ph, pl;
#pragma unroll
        for (int jj = 0; jj < 8; ++jj) {
          float v = av[g * 8 + jj];
          _Float16 h = (_Float16)v;
          ph[jj] = h;
          pl[jj] = (_Float16)(v - (float)h);
        }
        *(f16x8*)&Ah[base] = ph;
        *(f16x8*)&Al[base] = pl;
      }
    }
    __syncthreads();

    // ---- MFMA (wave w = k-slice) + prefetch next h chunk ----
    f16x8 ah[4], al[4];
#pragma unroll
    for (int rt = 0; rt < 4; ++rt) {
      ah[rt] = *(const f16x8*)&Ah[((w * 4 + rt) * 64 + lane) * 8];
      al[rt] = *(const f16x8*)&Al[((w * 4 + rt) * 64 + lane) * 8];
    }
    if (cc + 1 < CPS) {
      const float2* hc = h1p + (size_t)(split * CPS + cc + 1) * Epad;
      for (int idx = t; idx < EBs; idx += 256) hbuf[cur ^ 1][idx] = hc[p0b + idx];
    }
    size_t bbase = ((size_t)(kc * 4 + w) * 4) * 512;
#pragma unroll
    for (int c = 0; c < 4; ++c) {
      f16x8 bh = *(const f16x8*)&Bh[bbase + c * 512 + lane * 8];
      f16x8 bl = *(const f16x8*)&Bl[bbase + c * 512 + lane * 8];
#pragma unroll
      for (int rt = 0; rt < 4; ++rt) {
        acc[rt][c] = __builtin_amdgcn_mfma_f32_16x16x32_f16(ah[rt], bh, acc[rt][c], 0, 0, 0);
        acc[rt][c] = __builtin_amdgcn_mfma_f32_16x16x32_f16(ah[rt], bl, acc[rt][c], 0, 0, 0);
        acc[rt][c] = __builtin_amdgcn_mfma_f32_16x16x32_f16(al[rt], bh, acc[rt][c], 0, 0, 0);
      }
    }
    __syncthreads();
    if (cc + 1 < CPS) cur ^= 1;
  }

  // ---- epilogue: atomic accumulate (split-K) ----
  const int qrow = (lane >> 4) * 4, col = lane & 15;
#pragma unroll
  for (int rt = 0; rt < 4; ++rt) {
#pragma unroll
    for (int r = 0; r < 4; ++r) {
      int nn = n0 + rt * 16 + qrow + r;
      if (nn < N) {
        float* ap = agg2 + (size_t)nn * 64 + col;
#pragma unroll
        for (int c = 0; c < 4; ++c) atomicAdd(ap + c * 16, acc[rt][c][r]);
      }
    }
  }
}

// GRU step (16 nodes/block, 4 per wave): m = relu(agg2+conv_b); out <- GRU
__global__ __launch_bounds__(256) void k_gru(
    const float* __restrict__ agg2, const float* __restrict__ conv_b,
    const float* __restrict__ gw_ih, const float* __restrict__ gw_hh,
    const float* __restrict__ gb_ih, const float* __restrict__ gb_hh,
    float* __restrict__ outn, int N) {
  __shared__ float wT[32 * 385];
  const int t = threadIdx.x;
  const int wv = t >> 6, d = t & 63;
  const int nbase = blockIdx.x * 16 + wv * 4;
  float m_d[4], h_d[4];
  bool act[4];
#pragma unroll
  for (int j = 0; j < 4; ++j) {
    int n = nbase + j;
    act[j] = (n < N);
    m_d[j] = act[j] ? fmaxf(agg2[(size_t)n * 64 + d] + conv_b[d], 0.f) : 0.f;
    h_d[j] = act[j] ? outn[(size_t)n * 64 + d] : 0.f;
  }
  float ir[4] = {0, 0, 0, 0}, iz[4] = {0, 0, 0, 0}, in_[4] = {0, 0, 0, 0};
  float hr[4] = {0, 0, 0, 0}, hz[4] = {0, 0, 0, 0}, hn[4] = {0, 0, 0, 0};
  for (int half = 0; half < 2; ++half) {
    __syncthreads();
    for (int idx = t; idx < 192 * 32; idx += 256) {
      int g = idx >> 5, kl = idx & 31;
      wT[kl * 385 + g] = gw_ih[g * 64 + half * 32 + kl];
      wT[kl * 385 + 192 + g] = gw_hh[g * 64 + half * 32 + kl];
    }
    __syncthreads();
#pragma unroll
    for (int kl = 0; kl < 32; ++kl) {
      int k = half * 32 + kl;
      const float* row = &wT[kl * 385];
      float r0 = row[d], r1 = row[64 + d], r2 = row[128 + d];
      float r3 = row[192 + d], r4 = row[256 + d], r5 = row[320 + d];
#pragma unroll
      for (int j = 0; j < 4; ++j) {
        float mk = __shfl(m_d[j], k);
        float hk = __shfl(h_d[j], k);
        ir[j] += r0 * mk;
        iz[j] += r1 * mk;
        in_[j] += r2 * mk;
        hr[j] += r3 * hk;
        hz[j] += r4 * hk;
        hn[j] += r5 * hk;
      }
    }
  }
#pragma unroll
  for (int j = 0; j < 4; ++j) {
    if (act[j]) {
      int n = nbase + j;
      float r = 1.f / (1.f + expf(-(ir[j] + gb_ih[d] + hr[j] + gb_hh[d])));
      float z = 1.f / (1.f + expf(-(iz[j] + gb_ih[64 + d] + hz[j] + gb_hh[64 + d])));
      float nn = tanhf(in_[j] + gb_ih[128 + d] + r * (hn[j] + gb_hh[128 + d]));
      outn[(size_t)n * 64 + d] = (1.f - z) * nn + z * h_d[j];
    }
  }
}

// ---------------- fused Set2Set (3 steps) + readout, one block per graph ---
__global__ __launch_bounds__(256) void k_s2s(
    const float* __restrict__ outn, const int* __restrict__ gptr,
    const float* __restrict__ w_ih, const float* __restrict__ w_hh,
    const float* __restrict__ b_ih, const float* __restrict__ b_hh,
    const float* __restrict__ w1, const float* __restrict__ b1,
    const float* __restrict__ w2, const float* __restrict__ b2,
    float* __restrict__ y) {
  __shared__ float q[128];
  __shared__ float hsL[64];
  __shared__ float csL[64];
  __shared__ float gate[256];
  __shared__ float red[4][66];  // per-wave: m, den, racc[64]
  const int b = blockIdx.x, t = threadIdx.x;
  const int wv = t >> 6, d = t & 63;
  const int n0 = gptr[b], n1 = gptr[b + 1];
  if (t < 128) q[t] = 0.f;
  if (t < 64) { hsL[t] = 0.f; csL[t] = 0.f; }
  __syncthreads();

  for (int step = 0; step < 3; ++step) {
    // LSTM gates: 256 threads = 256 gate units
    float acc = b_ih[t] + b_hh[t];
    const float* wi = w_ih + t * 128;
    const float* wh = w_hh + t * 64;
#pragma unroll 4
    for (int k = 0; k < 128; ++k) acc += wi[k] * q[k];
#pragma unroll 4
    for (int k = 0; k < 64; ++k) acc += wh[k] * hsL[k];
    gate[t] = acc;
    __syncthreads();
    if (t < 64) {
      float ig = gate[t], fg = gate[64 + t], gg = gate[128 + t],
            og = gate[192 + t];
      float c = csL[t];
      float si = 1.f / (1.f + expf(-ig));
      float sf = 1.f / (1.f + expf(-fg));
      float so = 1.f / (1.f + expf(-og));
      float cn = sf * c + si * tanhf(gg);
      csL[t] = cn;
      hsL[t] = so * tanhf(cn);
    }
    __syncthreads();

    // attention: wave wv handles nodes n0+wv, n0+wv+4, ... (online softmax)
    float qd = hsL[d];
    float mx = -3.4e38f, den = 0.f, racc = 0.f;
    for (int nn = n0 + wv; nn < n1; nn += 4) {
      float od = outn[(size_t)nn * 64 + d];
      float v = od * qd;
      for (int s = 32; s > 0; s >>= 1) v += __shfl_xor(v, s);
      float mnew = fmaxf(mx, v);
      float scale = expf(mx - mnew);
      float a = expf(v - mnew);
      den = den * scale + a;
      racc = racc * scale + a * od;
      mx = mnew;
    }
    if (d == 0) { red[wv][0] = mx; red[wv][1] = den; }
    red[wv][2 + d] = racc;
    __syncthreads();
    if (t < 64) {
      float M = fmaxf(fmaxf(red[0][0], red[1][0]), fmaxf(red[2][0], red[3][0]));
      float dd = 0.f, rr = 0.f;
#pragma unroll
      for (int ww = 0; ww < 4; ++ww) {
        float sc = expf(red[ww][0] - M);
        dd += red[ww][1] * sc;
        rr += red[ww][2 + t] * sc;
      }
      float r = (dd > 0.f) ? rr / dd : 0.f;
      q[t] = hsL[t];
      q[64 + t] = r;
    }
    __syncthreads();
  }

  // readout: y[b] = relu(q @ lin1^T + b1) @ lin2^T + b2
  if (t < 64) {
    float acc = b1[t];
    const float* wr = w1 + t * 128;
#pragma unroll 4
    for (int k = 0; k < 128; ++k) acc += wr[k] * q[k];
    acc = fmaxf(acc, 0.f) * w2[t];
    for (int s = 32; s > 0; s >>= 1) acc += __shfl_xor(acc, s);
    if (t == 0) y[b] = acc + b2[0];
  }
}

extern "C" void kernel_launch(void* const* d_in, const int* in_sizes, int n_in,
                              void* d_out, int out_size, void* d_ws,
                              size_t ws_size, hipStream_t stream) {
  (void)n_in; (void)out_size; (void)ws_size;
  const float* x      = (const float*)d_in[0];
  const int*   eidx   = (const int*)d_in[1];
  const float* eattr  = (const float*)d_in[2];
  const int*   batch  = (const int*)d_in[3];
  const float* lin0_w = (const float*)d_in[4];
  const float* lin0_b = (const float*)d_in[5];
  const float* nn1_w  = (const float*)d_in[6];
  const float* nn1_b  = (const float*)d_in[7];
  const float* nn2_w  = (const float*)d_in[8];
  const float* nn2_b  = (const float*)d_in[9];
  const float* root_w = (const float*)d_in[10];
  const float* conv_b = (const float*)d_in[11];
  const float* gw_ih  = (const float*)d_in[12];
  const float* gw_hh  = (const float*)d_in[13];
  const float* gb_ih  = (const float*)d_in[14];
  const float* gb_hh  = (const float*)d_in[15];
  const float* lw_ih  = (const float*)d_in[16];
  const float* lw_hh  = (const float*)d_in[17];
  const float* lb_ih  = (const float*)d_in[18];
  const float* lb_hh  = (const float*)d_in[19];
  const float* lin1_w = (const float*)d_in[20];
  const float* lin1_b = (const float*)d_in[21];
  const float* lin2_w = (const float*)d_in[22];
  const float* lin2_b = (const float*)d_in[23];

  const int N = in_sizes[0] / 11;
  const int E = in_sizes[1] / 2;
  const int B = 512;
  const int Epad = (E + 127) & ~127;

  size_t off = 0;
  auto bump = [&](size_t bytes) {
    size_t o = off;
    off += (bytes + 255) & ~(size_t)255;
    return o;
  };
  char* base = (char*)d_ws;
  float*     outn   = (float*)(base + bump((size_t)N * 64 * 4));
  float*     agg2   = (float*)(base + bump((size_t)N * 64 * 4));
  float2*    h1p    = (float2*)(base + bump((size_t)64 * Epad * 8));
  _Float16*  Bh     = (_Float16*)(base + bump((size_t)BFRAG_TOTAL * 2));
  _Float16*  Bl     = (_Float16*)(base + bump((size_t)BFRAG_TOTAL * 2));
  int*       cnt    = (int*)(base + bump((size_t)2 * N * 4));  // cnt + fill
  int*       fill   = cnt + N;
  int*       dptr   = (int*)(base + bump((size_t)(N + 1) * 4));
  int*       srcs_s = (int*)(base + bump((size_t)E * 4));
  int*       eord   = (int*)(base + bump((size_t)E * 4));
  int*       gptr   = (int*)(base + bump((size_t)(B + 1) * 4));

  hipMemsetAsync(cnt, 0, (size_t)2 * N * 4, stream);

  k_gptr<<<(N + 255) / 256, 256, 0, stream>>>(batch, gptr, N, B);
  k_cnt<<<(E + 255) / 256, 256, 0, stream>>>(eidx, cnt, E);
  k_scan<<<1, 1024, 0, stream>>>(cnt, dptr, N);
  k_fill<<<(E + 255) / 256, 256, 0, stream>>>(eidx, dptr, fill, srcs_s, eord, E);
  k_h1t<<<(E + 127) / 128, 256, 0, stream>>>(eattr, eord, nn1_w, nn1_b, h1p, E,
                                             Epad);
  k_bsplit<<<(BFRAG_TOTAL + 255) / 256, 256, 0, stream>>>(nn2_w, nn2_b, root_w,
                                                          Bh, Bl);
  k_lin0<<<(N * 64 + 255) / 256, 256, 0, stream>>>(x, lin0_w, lin0_b, outn, N);

  const int NBLK = (N + 63) / 64;
  for (int it = 0; it < 3; ++it) {
    hipMemsetAsync(agg2, 0, (size_t)N * 64 * 4, stream);
    k_fused<<<dim3(NBLK, SPLITK), 256, 0, stream>>>(outn, h1p, dptr, srcs_s, Bh,
                                                    Bl, agg2, N, Epad);
    k_gru<<<(N + 15) / 16, 256, 0, stream>>>(agg2, conv_b, gw_ih, gw_hh, gb_ih,
                                             gb_hh, outn, N);
  }

  k_s2s<<<B, 256, 0, stream>>>(outn, gptr, lw_ih, lw_hh, lb_ih, lb_hh, lin1_w,
                               lin1_b, lin2_w, lin2_b, (float*)d_out);
}

// Round 10
// 1049.583 us; speedup vs baseline: 1.4803x; 1.0831x over previous
//
#include <hip/hip_runtime.h>
#include <math.h>

// ---------------------------------------------------------------------------
// MPNN (NNConv+GRU x3, Set2Set x3, readout).
// R10: R4 k_fused (M=64, LDS A-frags, split-K x4) + 2-edge-unrolled A-build,
// h1p pre-scaled by 1/deg(dst) (no per-chunk inv multiply), coalesced
// k_bsplit (LDS transpose per kc). Fused Set2Set+readout.
// ---------------------------------------------------------------------------

typedef _Float16 f16x8 __attribute__((ext_vector_type(8)));
typedef float f32x4 __attribute__((ext_vector_type(4)));

#define BFRAG_TOTAL (66 * 4 * 4 * 64 * 8)  // 540672 halves per array
#define EMAXB 384                          // max edges per 64-node block (LDS)
#define SPLITK 4
#define CPS 16                             // chunks per split (64/SPLITK)

// graph segment pointers from sorted batch
__global__ void k_gptr(const int* __restrict__ batch, int* __restrict__ gptr,
                       int N, int B) {
  int n = blockIdx.x * 256 + threadIdx.x;
  if (n >= N) return;
  int b = batch[n];
  int bp = (n == 0) ? -1 : batch[n - 1];
  for (int g = bp + 1; g <= b; ++g) gptr[g] = n;
  if (n == N - 1) {
    for (int g = b + 1; g <= B; ++g) gptr[g] = N;
  }
}

__global__ void k_cnt(const int* __restrict__ eidx, int* __restrict__ cnt, int E) {
  int e = blockIdx.x * 256 + threadIdx.x;
  if (e < E) atomicAdd(&cnt[eidx[E + e]], 1);
}

// single-block scan via wave shuffles -> dptr (exclusive CSR pointers)
__global__ __launch_bounds__(1024) void k_scan(const int* __restrict__ cnt,
                                               int* __restrict__ dptr, int N) {
  __shared__ int wsum[16];
  int t = threadIdx.x;
  int lane = t & 63, wid = t >> 6;
  if (t == 0) dptr[0] = 0;
  int running = 0;
  for (int base = 0; base < N; base += 1024) {
    int x = (base + t < N) ? cnt[base + t] : 0;
#pragma unroll
    for (int d = 1; d < 64; d <<= 1) {
      int u = __shfl_up(x, d, 64);
      if (lane >= d) x += u;
    }
    if (lane == 63) wsum[wid] = x;
    __syncthreads();
    if (wid == 0) {
      int y = (lane < 16) ? wsum[lane] : 0;
#pragma unroll
      for (int d = 1; d < 16; d <<= 1) {
        int u = __shfl_up(y, d, 64);
        if (lane >= d) y += u;
      }
      if (lane < 16) wsum[lane] = y;
    }
    __syncthreads();
    int add = running + (wid > 0 ? wsum[wid - 1] : 0);
    if (base + t < N) dptr[base + t + 1] = add + x;
    running += wsum[15];
    __syncthreads();
  }
}

__global__ void k_fill(const int* __restrict__ eidx, const int* __restrict__ dptr,
                       int* __restrict__ fill, int* __restrict__ srcs_s,
                       int* __restrict__ eord, int E) {
  int e = blockIdx.x * 256 + threadIdx.x;
  if (e >= E) return;
  int d = eidx[E + e];
  int pos = dptr[d] + atomicAdd(&fill[d], 1);
  srcs_s[pos] = eidx[e];
  eord[pos] = e;
}

// h1p[k>>1][pos] = invdeg(dst) * (h1[pos][2k'], h1[pos][2k'+1]) : k-major
__global__ __launch_bounds__(256) void k_h1t(const float* __restrict__ eattr,
                                             const int* __restrict__ eord,
                                             const int* __restrict__ eidx,
                                             const int* __restrict__ cnt,
                                             const float* __restrict__ nn1_w,
                                             const float* __restrict__ nn1_b,
                                             float2* __restrict__ h1p, int E,
                                             int Epad) {
  __shared__ float a5[128 * 5];
  __shared__ float w5[128 * 5];
  __shared__ float bb[128];
  __shared__ float idg[128];
  const int t = threadIdx.x;
  const int p0 = blockIdx.x * 128;
  for (int idx = t; idx < 640; idx += 256) w5[idx] = nn1_w[idx];
  if (t < 128) bb[t] = nn1_b[t];
  if (t < 128) {
    int pos = p0 + t;
    if (pos < E) {
      int e = eord[pos];
      const float* a = eattr + (size_t)e * 5;
#pragma unroll
      for (int q = 0; q < 5; ++q) a5[t * 5 + q] = a[q];
      int dg = cnt[eidx[E + e]];
      idg[t] = 1.f / (float)(dg > 1 ? dg : 1);
    } else {
#pragma unroll
      for (int q = 0; q < 5; ++q) a5[t * 5 + q] = 0.f;
      idg[t] = 0.f;
    }
  }
  __syncthreads();
  const int pl = t & 127, jh = (t >> 7) * 64;
  const int pos = p0 + pl;
  if (pos >= E) return;
  float a0 = a5[pl * 5 + 0], a1 = a5[pl * 5 + 1], a2 = a5[pl * 5 + 2],
        a3 = a5[pl * 5 + 3], a4 = a5[pl * 5 + 4];
  float inv = idg[pl];
#pragma unroll 8
  for (int jj = 0; jj < 64; jj += 2) {
    int j = jh + jj;
    const float* w0 = &w5[j * 5];
    float v0 = fmaxf(bb[j] + a0 * w0[0] + a1 * w0[1] + a2 * w0[2] + a3 * w0[3] +
                         a4 * w0[4], 0.f);
    const float* w1 = &w5[(j + 1) * 5];
    float v1 = fmaxf(bb[j + 1] + a0 * w1[0] + a1 * w1[1] + a2 * w1[2] +
                         a3 * w1[3] + a4 * w1[4], 0.f);
    h1p[(size_t)(j >> 1) * Epad + pos] = make_float2(v0 * inv, v1 * inv);
  }
}

// Pre-split Wbig into fp16 hi/lo in MFMA B-fragment order, one kc per block.
// flat idx = (((kc*4 + w)*4 + c)*64 + lane)*8 + j
__global__ __launch_bounds__(256) void k_bsplit(
    const float* __restrict__ nn2_w, const float* __restrict__ nn2_b,
    const float* __restrict__ root_w, _Float16* __restrict__ Bh,
    _Float16* __restrict__ Bl) {
  __shared__ float lds[4096 * 2];
  const int kc = blockIdx.x;
  const int t = threadIdx.x;
  if (kc < 64) {
    for (int r = t; r < 4096; r += 256) {
      float2 v = *(const float2*)&nn2_w[(size_t)r * 128 + kc * 2];
      lds[r * 2] = v.x;
      lds[r * 2 + 1] = v.y;
    }
  } else if (kc == 64) {
    for (int r = t; r < 4096; r += 256) {
      lds[r * 2] = nn2_b[r];
      lds[r * 2 + 1] = 0.f;
    }
  } else {
    for (int r = t; r < 4096; r += 256) {
      int i = r >> 6, o = r & 63;
      lds[r * 2] = root_w[o * 64 + i];
      lds[r * 2 + 1] = 0.f;
    }
  }
  __syncthreads();
  for (int slot = t; slot < 1024; slot += 256) {
    int lane = slot & 63, c = (slot >> 6) & 3, w = slot >> 8;
    f16x8 ph, pl;
#pragma unroll
    for (int j = 0; j < 8; ++j) {
      int m = w * 32 + ((lane >> 4) << 3) + j;
      int o = c * 16 + (lane & 15);
      int i = m & 63, kl = m >> 6;
      float v = lds[(i * 64 + o) * 2 + kl];
      _Float16 h = (_Float16)v;
      ph[j] = h;
      pl[j] = (_Float16)(v - (float)h);
    }
    size_t base = (((size_t)kc * 4 + w) * 4 + c) * 512 + (size_t)lane * 8;
    *(f16x8*)&Bh[base] = ph;
    *(f16x8*)&Bl[base] = pl;
  }
}

// out = relu(x @ lin0_w^T + lin0_b)
__global__ void k_lin0(const float* __restrict__ x, const float* __restrict__ w,
                       const float* __restrict__ b, float* __restrict__ outn, int N) {
  int gid = blockIdx.x * 256 + threadIdx.x;
  int n = gid >> 6, d = gid & 63;
  if (n >= N) return;
  const float* xr = x + (size_t)n * 11;
  const float* wr = w + d * 11;
  float acc = b[d];
#pragma unroll
  for (int f = 0; f < 11; ++f) acc += xr[f] * wr[f];
  outn[(size_t)n * 64 + d] = fmaxf(acc, 0.f);
}

// ---------------- fused NNConv (M=64, LDS A-frags, split-K x4) -------------
__global__ __launch_bounds__(256, 3) void k_fused(
    const float* __restrict__ outn, const float2* __restrict__ h1p,
    const int* __restrict__ dptr, const int* __restrict__ srcs_s,
    const _Float16* __restrict__ Bh, const _Float16* __restrict__ Bl,
    float* __restrict__ agg2, int N, int Epad) {
  __shared__ __align__(16) _Float16 Ah[16 * 64 * 8];  // 16 KB
  __shared__ __align__(16) _Float16 Al[16 * 64 * 8];  // 16 KB
  __shared__ __align__(16) float2 hbuf[2][EMAXB];     // 6 KB
  __shared__ int sSrc[EMAXB];                         // 1.5 KB

  const int t = threadIdx.x;
  const int w = t >> 6, lane = t & 63;
  const int nl = t >> 2;   // builder node (0..63)
  const int iq = t & 3;    // i-quarter (16 cols)
  const int split = blockIdx.y;
  const int n0 = blockIdx.x * 64;
  const int n = n0 + nl;
  const bool nvalid = (n < N);
  const int hi_n = (n0 + 64 > N) ? N : (n0 + 64);
  const int p0b = dptr[n0];
  const int p1b = dptr[hi_n];
  const int EB = p1b - p0b;
  const bool useLds = (EB <= EMAXB);
  int p0 = 0, p1 = 0;
  if (nvalid) { p0 = dptr[n]; p1 = dptr[n + 1]; }
  const float inv = 1.f / (float)((p1 - p0) > 1 ? (p1 - p0) : 1);
  const int rt_b = nl >> 4, nm = nl & 15;
  const int EBs = useLds ? EB : 0;

  // ---- stage src list + first h chunk ----
  for (int idx = t; idx < EBs; idx += 256) sSrc[idx] = srcs_s[p0b + idx];
  {
    const float2* hc = h1p + (size_t)(split * CPS) * Epad;
    for (int idx = t; idx < EBs; idx += 256) hbuf[0][idx] = hc[p0b + idx];
  }
  __syncthreads();

  f32x4 acc[4][4];
#pragma unroll
  for (int a = 0; a < 4; ++a)
#pragma unroll
    for (int c = 0; c < 4; ++c) acc[a][c] = (f32x4)(0.f);

  const int niter = (split < 2) ? (CPS + 1) : CPS;
  int cur = 0;
  for (int cc = 0; cc < niter; ++cc) {
    const int mode = (cc < CPS) ? 0 : ((split == 0) ? 1 : 2);
    const int kc = (cc < CPS) ? (split * CPS + cc) : (64 + split);

    // ---- build this thread's 32 A-values (2 kl x 16 i) ----
    float av0[16], av1[16];
#pragma unroll
    for (int j = 0; j < 16; ++j) { av0[j] = 0.f; av1[j] = 0.f; }

    if (mode == 0) {
      const float2* hc = h1p + (size_t)kc * Epad;
      int pos = p0;
      // 2-edge unrolled: both s-row loads issued independently
      for (; pos + 2 <= p1; pos += 2) {
        int ea = pos - p0b, eb = ea + 1;
        float2 ha = useLds ? hbuf[cur][ea] : hc[pos];
        float2 hb = useLds ? hbuf[cur][eb] : hc[pos + 1];
        int sa = useLds ? sSrc[ea] : srcs_s[pos];
        int sb = useLds ? sSrc[eb] : srcs_s[pos + 1];
        const float4* pa = (const float4*)(outn + (size_t)sa * 64 + iq * 16);
        const float4* pb = (const float4*)(outn + (size_t)sb * 64 + iq * 16);
        float4 a0 = pa[0], a1 = pa[1], a2 = pa[2], a3 = pa[3];
        float4 b0 = pb[0], b1 = pb[1], b2 = pb[2], b3 = pb[3];
        float sva[16] = {a0.x, a0.y, a0.z, a0.w, a1.x, a1.y, a1.z, a1.w,
                         a2.x, a2.y, a2.z, a2.w, a3.x, a3.y, a3.z, a3.w};
        float svb[16] = {b0.x, b0.y, b0.z, b0.w, b1.x, b1.y, b1.z, b1.w,
                         b2.x, b2.y, b2.z, b2.w, b3.x, b3.y, b3.z, b3.w};
#pragma unroll
        for (int j = 0; j < 16; ++j) {
          av0[j] += ha.x * sva[j] + hb.x * svb[j];
          av1[j] += ha.y * sva[j] + hb.y * svb[j];
        }
      }
      if (pos < p1) {
        int ea = pos - p0b;
        float2 ha = useLds ? hbuf[cur][ea] : hc[pos];
        int sa = useLds ? sSrc[ea] : srcs_s[pos];
        const float4* pa = (const float4*)(outn + (size_t)sa * 64 + iq * 16);
        float4 a0 = pa[0], a1 = pa[1], a2 = pa[2], a3 = pa[3];
        float sva[16] = {a0.x, a0.y, a0.z, a0.w, a1.x, a1.y, a1.z, a1.w,
                         a2.x, a2.y, a2.z, a2.w, a3.x, a3.y, a3.z, a3.w};
#pragma unroll
        for (int j = 0; j < 16; ++j) {
          av0[j] += ha.x * sva[j];
          av1[j] += ha.y * sva[j];
        }
      }
    } else if (mode == 1) {  // bias chunk: A[n] = inv * sum_e s[src]
      for (int pos = p0; pos < p1; ++pos) {
        int src = useLds ? sSrc[pos - p0b] : srcs_s[pos];
        const float4* sp = (const float4*)(outn + (size_t)src * 64 + iq * 16);
        float4 s0 = sp[0], s1 = sp[1], s2 = sp[2], s3 = sp[3];
        float sv[16] = {s0.x, s0.y, s0.z, s0.w, s1.x, s1.y, s1.z, s1.w,
                        s2.x, s2.y, s2.z, s2.w, s3.x, s3.y, s3.z, s3.w};
#pragma unroll
        for (int j = 0; j < 16; ++j) av0[j] += sv[j];
      }
#pragma unroll
      for (int j = 0; j < 16; ++j) av0[j] *= inv;
    } else {  // root chunk: A[n] = outn[n]
      if (nvalid) {
        const float4* sp = (const float4*)(outn + (size_t)n * 64 + iq * 16);
        float4 s0 = sp[0], s1 = sp[1], s2 = sp[2], s3 = sp[3];
        float sv[16] = {s0.x, s0.y, s0.z, s0.w, s1.x, s1.y, s1.z, s1.w,
                        s2.x, s2.y, s2.z, s2.w, s3.x, s3.y, s3.z, s3.w};
#pragma unroll
        for (int j = 0; j < 16; ++j) av0[j] = sv[j];
      }
    }

    // ---- split fp16 hi/lo, write A-frag order ----
#pragma unroll
    for (int kl = 0; kl < 2; ++kl) {
      const float* av = kl ? av1 : av0;
      int wb = kl * 2 + (iq >> 1);
#pragma unroll
      for (int g = 0; g < 2; ++g) {
        int q = (iq & 1) * 2 + g;
        int base = ((wb * 4 + rt_b) * 64 + (q << 4) + nm) * 8;
        f16x8 ph, pl;
#pragma unroll
        for (int jj = 0; jj < 8; ++jj) {
          float v = av[g * 8 + jj];
          _Float16 h = (_Float16)v;
          ph[jj] = h;
          pl[jj] = (_Float16)(v - (float)h);
        }
        *(f16x8*)&Ah[base] = ph;
        *(f16x8*)&Al[base] = pl;
      }
    }
    __syncthreads();

    // ---- MFMA (wave w = k-slice) + prefetch next h chunk ----
    f16x8 ah[4], al[4];
#pragma unroll
    for (int rt = 0; rt < 4; ++rt) {
      ah[rt] = *(const f16x8*)&Ah[((w * 4 + rt) * 64 + lane) * 8];
      al[rt] = *(const f16x8*)&Al[((w * 4 + rt) * 64 + lane) * 8];
    }
    if (cc + 1 < CPS) {
      const float2* hc = h1p + (size_t)(split * CPS + cc + 1) * Epad;
      for (int idx = t; idx < EBs; idx += 256) hbuf[cur ^ 1][idx] = hc[p0b + idx];
    }
    size_t bbase = ((size_t)(kc * 4 + w) * 4) * 512;
#pragma unroll
    for (int c = 0; c < 4; ++c) {
      f16x8 bh = *(const f16x8*)&Bh[bbase + c * 512 + lane * 8];
      f16x8 bl = *(const f16x8*)&Bl[bbase + c * 512 + lane * 8];
#pragma unroll
      for (int rt = 0; rt < 4; ++rt) {
        acc[rt][c] = __builtin_amdgcn_mfma_f32_16x16x32_f16(ah[rt], bh, acc[rt][c], 0, 0, 0);
        acc[rt][c] = __builtin_amdgcn_mfma_f32_16x16x32_f16(ah[rt], bl, acc[rt][c], 0, 0, 0);
        acc[rt][c] = __builtin_amdgcn_mfma_f32_16x16x32_f16(al[rt], bh, acc[rt][c], 0, 0, 0);
      }
    }
    __syncthreads();
    if (cc + 1 < CPS) cur ^= 1;
  }

  // ---- epilogue: atomic accumulate (split-K) ----
  const int qrow = (lane >> 4) * 4, col = lane & 15;
#pragma unroll
  for (int rt = 0; rt < 4; ++rt) {
#pragma unroll
    for (int r = 0; r < 4; ++r) {
      int nn = n0 + rt * 16 + qrow + r;
      if (nn < N) {
        float* ap = agg2 + (size_t)nn * 64 + col;
#pragma unroll
        for (int c = 0; c < 4; ++c) atomicAdd(ap + c * 16, acc[rt][c][r]);
      }
    }
  }
}

// GRU step (16 nodes/block, 4 per wave): m = relu(agg2+conv_b); out <- GRU
__global__ __launch_bounds__(256) void k_gru(
    const float* __restrict__ agg2, const float* __restrict__ conv_b,
    const float* __restrict__ gw_ih, const float* __restrict__ gw_hh,
    const float* __restrict__ gb_ih, const float* __restrict__ gb_hh,
    float* __restrict__ outn, int N) {
  __shared__ float wT[32 * 385];
  const int t = threadIdx.x;
  const int wv = t >> 6, d = t & 63;
  const int nbase = blockIdx.x * 16 + wv * 4;
  float m_d[4], h_d[4];
  bool act[4];
#pragma unroll
  for (int j = 0; j < 4; ++j) {
    int n = nbase + j;
    act[j] = (n < N);
    m_d[j] = act[j] ? fmaxf(agg2[(size_t)n * 64 + d] + conv_b[d], 0.f) : 0.f;
    h_d[j] = act[j] ? outn[(size_t)n * 64 + d] : 0.f;
  }
  float ir[4] = {0, 0, 0, 0}, iz[4] = {0, 0, 0, 0}, in_[4] = {0, 0, 0, 0};
  float hr[4] = {0, 0, 0, 0}, hz[4] = {0, 0, 0, 0}, hn[4] = {0, 0, 0, 0};
  for (int half = 0; half < 2; ++half) {
    __syncthreads();
    for (int idx = t; idx < 192 * 32; idx += 256) {
      int g = idx >> 5, kl = idx & 31;
      wT[kl * 385 + g] = gw_ih[g * 64 + half * 32 + kl];
      wT[kl * 385 + 192 + g] = gw_hh[g * 64 + half * 32 + kl];
    }
    __syncthreads();
#pragma unroll
    for (int kl = 0; kl < 32; ++kl) {
      int k = half * 32 + kl;
      const float* row = &wT[kl * 385];
      float r0 = row[d], r1 = row[64 + d], r2 = row[128 + d];
      float r3 = row[192 + d], r4 = row[256 + d], r5 = row[320 + d];
#pragma unroll
      for (int j = 0; j < 4; ++j) {
        float mk = __shfl(m_d[j], k);
        float hk = __shfl(h_d[j], k);
        ir[j] += r0 * mk;
        iz[j] += r1 * mk;
        in_[j] += r2 * mk;
        hr[j] += r3 * hk;
        hz[j] += r4 * hk;
        hn[j] += r5 * hk;
      }
    }
  }
#pragma unroll
  for (int j = 0; j < 4; ++j) {
    if (act[j]) {
      int n = nbase + j;
      float r = 1.f / (1.f + expf(-(ir[j] + gb_ih[d] + hr[j] + gb_hh[d])));
      float z = 1.f / (1.f + expf(-(iz[j] + gb_ih[64 + d] + hz[j] + gb_hh[64 + d])));
      float nn = tanhf(in_[j] + gb_ih[128 + d] + r * (hn[j] + gb_hh[128 + d]));
      outn[(size_t)n * 64 + d] = (1.f - z) * nn + z * h_d[j];
    }
  }
}

// ---------------- fused Set2Set (3 steps) + readout, one block per graph ---
__global__ __launch_bounds__(256) void k_s2s(
    const float* __restrict__ outn, const int* __restrict__ gptr,
    const float* __restrict__ w_ih, const float* __restrict__ w_hh,
    const float* __restrict__ b_ih, const float* __restrict__ b_hh,
    const float* __restrict__ w1, const float* __restrict__ b1,
    const float* __restrict__ w2, const float* __restrict__ b2,
    float* __restrict__ y) {
  __shared__ float q[128];
  __shared__ float hsL[64];
  __shared__ float csL[64];
  __shared__ float gate[256];
  __shared__ float red[4][66];  // per-wave: m, den, racc[64]
  const int b = blockIdx.x, t = threadIdx.x;
  const int wv = t >> 6, d = t & 63;
  const int n0 = gptr[b], n1 = gptr[b + 1];
  if (t < 128) q[t] = 0.f;
  if (t < 64) { hsL[t] = 0.f; csL[t] = 0.f; }
  __syncthreads();

  for (int step = 0; step < 3; ++step) {
    float acc = b_ih[t] + b_hh[t];
    const float* wi = w_ih + t * 128;
    const float* wh = w_hh + t * 64;
#pragma unroll 4
    for (int k = 0; k < 128; ++k) acc += wi[k] * q[k];
#pragma unroll 4
    for (int k = 0; k < 64; ++k) acc += wh[k] * hsL[k];
    gate[t] = acc;
    __syncthreads();
    if (t < 64) {
      float ig = gate[t], fg = gate[64 + t], gg = gate[128 + t],
            og = gate[192 + t];
      float c = csL[t];
      float si = 1.f / (1.f + expf(-ig));
      float sf = 1.f / (1.f + expf(-fg));
      float so = 1.f / (1.f + expf(-og));
      float cn = sf * c + si * tanhf(gg);
      csL[t] = cn;
      hsL[t] = so * tanhf(cn);
    }
    __syncthreads();

    float qd = hsL[d];
    float mx = -3.4e38f, den = 0.f, racc = 0.f;
    for (int nn = n0 + wv; nn < n1; nn += 4) {
      float od = outn[(size_t)nn * 64 + d];
      float v = od * qd;
      for (int s = 32; s > 0; s >>= 1) v += __shfl_xor(v, s);
      float mnew = fmaxf(mx, v);
      float scale = expf(mx - mnew);
      float a = expf(v - mnew);
      den = den * scale + a;
      racc = racc * scale + a * od;
      mx = mnew;
    }
    if (d == 0) { red[wv][0] = mx; red[wv][1] = den; }
    red[wv][2 + d] = racc;
    __syncthreads();
    if (t < 64) {
      float M = fmaxf(fmaxf(red[0][0], red[1][0]), fmaxf(red[2][0], red[3][0]));
      float dd = 0.f, rr = 0.f;
#pragma unroll
      for (int ww = 0; ww < 4; ++ww) {
        float sc = expf(red[ww][0] - M);
        dd += red[ww][1] * sc;
        rr += red[ww][2 + t] * sc;
      }
      float r = (dd > 0.f) ? rr / dd : 0.f;
      q[t] = hsL[t];
      q[64 + t] = r;
    }
    __syncthreads();
  }

  if (t < 64) {
    float acc = b1[t];
    const float* wr = w1 + t * 128;
#pragma unroll 4
    for (int k = 0; k < 128; ++k) acc += wr[k] * q[k];
    acc = fmaxf(acc, 0.f) * w2[t];
    for (int s = 32; s > 0; s >>= 1) acc += __shfl_xor(acc, s);
    if (t == 0) y[b] = acc + b2[0];
  }
}

extern "C" void kernel_launch(void* const* d_in, const int* in_sizes, int n_in,
                              void* d_out, int out_size, void* d_ws,
                              size_t ws_size, hipStream_t stream) {
  (void)n_in; (void)out_size; (void)ws_size;
  const float* x      = (const float*)d_in[0];
  const int*   eidx   = (const int*)d_in[1];
  const float* eattr  = (const float*)d_in[2];
  const int*   batch  = (const int*)d_in[3];
  const float* lin0_w = (const float*)d_in[4];
  const float* lin0_b = (const float*)d_in[5];
  const float* nn1_w  = (const float*)d_in[6];
  const float* nn1_b  = (const float*)d_in[7];
  const float* nn2_w  = (const float*)d_in[8];
  const float* nn2_b  = (const float*)d_in[9];
  const float* root_w = (const float*)d_in[10];
  const float* conv_b = (const float*)d_in[11];
  const float* gw_ih  = (const float*)d_in[12];
  const float* gw_hh  = (const float*)d_in[13];
  const float* gb_ih  = (const float*)d_in[14];
  const float* gb_hh  = (const float*)d_in[15];
  const float* lw_ih  = (const float*)d_in[16];
  const float* lw_hh  = (const float*)d_in[17];
  const float* lb_ih  = (const float*)d_in[18];
  const float* lb_hh  = (const float*)d_in[19];
  const float* lin1_w = (const float*)d_in[20];
  const float* lin1_b = (const float*)d_in[21];
  const float* lin2_w = (const float*)d_in[22];
  const float* lin2_b = (const float*)d_in[23];

  const int N = in_sizes[0] / 11;
  const int E = in_sizes[1] / 2;
  const int B = 512;
  const int Epad = (E + 127) & ~127;

  size_t off = 0;
  auto bump = [&](size_t bytes) {
    size_t o = off;
    off += (bytes + 255) & ~(size_t)255;
    return o;
  };
  char* base = (char*)d_ws;
  float*     outn   = (float*)(base + bump((size_t)N * 64 * 4));
  float*     agg2   = (float*)(base + bump((size_t)N * 64 * 4));
  float2*    h1p    = (float2*)(base + bump((size_t)64 * Epad * 8));
  _Float16*  Bh     = (_Float16*)(base + bump((size_t)BFRAG_TOTAL * 2));
  _Float16*  Bl     = (_Float16*)(base + bump((size_t)BFRAG_TOTAL * 2));
  int*       cnt    = (int*)(base + bump((size_t)2 * N * 4));  // cnt + fill
  int*       fill   = cnt + N;
  int*       dptr   = (int*)(base + bump((size_t)(N + 1) * 4));
  int*       srcs_s = (int*)(base + bump((size_t)E * 4));
  int*       eord   = (int*)(base + bump((size_t)E * 4));
  int*       gptr   = (int*)(base + bump((size_t)(B + 1) * 4));

  hipMemsetAsync(cnt, 0, (size_t)2 * N * 4, stream);

  k_gptr<<<(N + 255) / 256, 256, 0, stream>>>(batch, gptr, N, B);
  k_cnt<<<(E + 255) / 256, 256, 0, stream>>>(eidx, cnt, E);
  k_scan<<<1, 1024, 0, stream>>>(cnt, dptr, N);
  k_fill<<<(E + 255) / 256, 256, 0, stream>>>(eidx, dptr, fill, srcs_s, eord, E);
  k_h1t<<<(E + 127) / 128, 256, 0, stream>>>(eattr, eord, eidx, cnt, nn1_w,
                                             nn1_b, h1p, E, Epad);
  k_bsplit<<<66, 256, 0, stream>>>(nn2_w, nn2_b, root_w, Bh, Bl);
  k_lin0<<<(N * 64 + 255) / 256, 256, 0, stream>>>(x, lin0_w, lin0_b, outn, N);

  const int NBLK = (N + 63) / 64;
  for (int it = 0; it < 3; ++it) {
    hipMemsetAsync(agg2, 0, (size_t)N * 64 * 4, stream);
    k_fused<<<dim3(NBLK, SPLITK), 256, 0, stream>>>(outn, h1p, dptr, srcs_s, Bh,
                                                    Bl, agg2, N, Epad);
    k_gru<<<(N + 15) / 16, 256, 0, stream>>>(agg2, conv_b, gw_ih, gw_hh, gb_ih,
                                             gb_hh, outn, N);
  }

  k_s2s<<<B, 256, 0, stream>>>(outn, gptr, lw_ih, lw_hh, lb_ih, lb_hh, lin1_w,
                               lin1_b, lin2_w, lin2_b, (float*)d_out);
}